// Round 1
// baseline (10129.218 us; speedup 1.0000x reference)
//
#include <hip/hip_runtime.h>
#include <hip/hip_bf16.h>
#include <math.h>

// Problem constants (fixed by the harness):
// B=32, S=12, N=2048, F=1, H=128, G=64, O=1, P=3
#define NB 32      // batch
#define SS 12      // seq len
#define NN 2048    // nodes
#define HH 128     // hidden
#define GG 64      // gcn hidden
#define PP 3       // pred len
#define RR (NN*NB) // 65536 rows, node-major r = n*32 + b

// ---------------------------------------------------------------------------
// Kernel A: ax[m*32+b] = sum_n adj[m][n] * xt[b*sb + n*sn]
// one 64-lane wave per output; lanes stride n with float4.
__global__ __launch_bounds__(256) void axk(
    const float* __restrict__ adj,
    const float* __restrict__ xt, int xt_sb, int xt_sn,
    float* __restrict__ ax)
{
    int w = (blockIdx.x * 256 + threadIdx.x) >> 6;
    int lane = threadIdx.x & 63;
    int m = w >> 5, b = w & 31;
    const float4* arow = (const float4*)(adj + (size_t)m * NN);
    float s = 0.f;
    if (xt_sn == 1) {
        const float4* xrow = (const float4*)(xt + (size_t)b * xt_sb);
#pragma unroll
        for (int k = 0; k < 8; ++k) {
            float4 a4 = arow[lane + 64*k];
            float4 x4 = xrow[lane + 64*k];
            s += a4.x*x4.x + a4.y*x4.y + a4.z*x4.z + a4.w*x4.w;
        }
    } else {
#pragma unroll
        for (int k = 0; k < 8; ++k) {
            float4 a4 = arow[lane + 64*k];
            size_t n0 = (size_t)(lane + 64*k) * 4;
            s += a4.x * xt[(n0+0)*xt_sn + (size_t)b*xt_sb];
            s += a4.y * xt[(n0+1)*xt_sn + (size_t)b*xt_sb];
            s += a4.z * xt[(n0+2)*xt_sn + (size_t)b*xt_sb];
            s += a4.w * xt[(n0+3)*xt_sn + (size_t)b*xt_sb];
        }
    }
#pragma unroll
    for (int off = 32; off; off >>= 1) s += __shfl_xor(s, off);
    if (lane == 0) ax[(size_t)m*32 + b] = s;
}

// ---------------------------------------------------------------------------
// Kernel T1: t1[r][j] = sum_g relu(ax[r]*Wg1[g] + bg1[g]) * Wg2[g][j]
// (fused GCN layer 1 + layer-2 weight mul; b_g2 is added after propagation)
#define T1_ROWS 16
__global__ __launch_bounds__(256) void t1k(
    const float* __restrict__ ax,
    const float* __restrict__ Wg1, const float* __restrict__ bg1,
    const float* __restrict__ Wg2,
    float* __restrict__ t1)
{
    __shared__ float w2[GG*HH];
    __shared__ float w1[GG], b1[GG];
    int tid = threadIdx.x;
#pragma unroll
    for (int l = 0; l < 8; ++l)
        ((float4*)w2)[tid + 256*l] = ((const float4*)Wg2)[tid + 256*l];
    if (tid < GG) { w1[tid] = Wg1[tid]; b1[tid] = bg1[tid]; }
    __syncthreads();
    int j = tid & 127, rsub = tid >> 7;
    int r0 = blockIdx.x * T1_ROWS;
    for (int p = 0; p < T1_ROWS/2; ++p) {
        int row = r0 + p*2 + rsub;
        float a = ax[row];
        float s = 0.f;
#pragma unroll 16
        for (int g = 0; g < GG; ++g) {
            float rg = fmaxf(fmaf(a, w1[g], b1[g]), 0.f);
            s = fmaf(rg, w2[g*HH + j], s);
        }
        t1[(size_t)row*HH + j] = s;
    }
}

// ---------------------------------------------------------------------------
// Generic fp32 tiled GEMM: C[M x Nc] = A[M x K] * B[K x Nc] + bias[col % period]
// 128x128 tile, K-chunk 32, 8x8 micro-tile per thread (256 threads).
__global__ __launch_bounds__(256) void gemm_tile(
    const float* __restrict__ A, int lda,
    const float* __restrict__ Bm, int ldb,
    float* __restrict__ C, int ldc,
    int K,
    const float* __restrict__ bias, int bias_period)
{
    const int m0 = blockIdx.y * 128;
    const int n0 = blockIdx.x * 128;
    __shared__ float a_t[32][132];  // [k][m], +4 pad keeps 16B align, breaks stride
    __shared__ float b_t[32][132];  // [k][n]
    const int tid = threadIdx.x;
    const int tx = tid & 15;
    const int ty = tid >> 4;
    float acc[8][8];
#pragma unroll
    for (int i = 0; i < 8; ++i)
#pragma unroll
        for (int j = 0; j < 8; ++j) acc[i][j] = 0.f;

    for (int k0 = 0; k0 < K; k0 += 32) {
        {
            int lrow = tid >> 3, lc4 = tid & 7;
#pragma unroll
            for (int p = 0; p < 4; ++p) {
                int row = lrow + p*32;
                float4 v = *(const float4*)(A + (size_t)(m0+row)*lda + k0 + lc4*4);
                a_t[lc4*4+0][row] = v.x; a_t[lc4*4+1][row] = v.y;
                a_t[lc4*4+2][row] = v.z; a_t[lc4*4+3][row] = v.w;
            }
            int brow = tid >> 5, bc4 = tid & 31;
#pragma unroll
            for (int p = 0; p < 4; ++p) {
                int kk = brow + p*8;
                float4 v = *(const float4*)(Bm + (size_t)(k0+kk)*ldb + n0 + bc4*4);
                *(float4*)&b_t[kk][bc4*4] = v;
            }
        }
        __syncthreads();
#pragma unroll 8
        for (int k = 0; k < 32; ++k) {
            float a[8], b[8];
            *(float4*)&a[0] = *(const float4*)&a_t[k][ty*8];
            *(float4*)&a[4] = *(const float4*)&a_t[k][ty*8+4];
            *(float4*)&b[0] = *(const float4*)&b_t[k][tx*8];
            *(float4*)&b[4] = *(const float4*)&b_t[k][tx*8+4];
#pragma unroll
            for (int i = 0; i < 8; ++i)
#pragma unroll
                for (int j = 0; j < 8; ++j)
                    acc[i][j] = fmaf(a[i], b[j], acc[i][j]);
        }
        __syncthreads();
    }
    float bv[8];
#pragma unroll
    for (int j = 0; j < 8; ++j)
        bv[j] = bias ? bias[(n0 + tx*8 + j) % bias_period] : 0.f;
#pragma unroll
    for (int i = 0; i < 8; ++i) {
        int row = m0 + ty*8 + i;
        float4 o0, o1;
        o0.x = acc[i][0]+bv[0]; o0.y = acc[i][1]+bv[1];
        o0.z = acc[i][2]+bv[2]; o0.w = acc[i][3]+bv[3];
        o1.x = acc[i][4]+bv[4]; o1.y = acc[i][5]+bv[5];
        o1.z = acc[i][6]+bv[6]; o1.w = acc[i][7]+bv[7];
        *(float4*)(C + (size_t)row*ldc + n0 + tx*8)     = o0;
        *(float4*)(C + (size_t)row*ldc + n0 + tx*8 + 4) = o1;
    }
}

// ---------------------------------------------------------------------------
// Kernel GXGATE: for 32 rows/block: gx = xg_row @ W_ih + b_ih  (32x384, K=128)
// then fused GRU gate update, h overwritten in-place (row-elementwise safe).
// g2 holds gh = h @ W_hh + b_hh (from gemm_tile).
__device__ __forceinline__ float sigmoidf_(float x) {
    return 1.f / (1.f + __expf(-x));
}
__global__ __launch_bounds__(256) void gxgate(
    const float* __restrict__ xg,
    const float* __restrict__ Wih,   // 128 x 384
    const float* __restrict__ bih,   // 384
    const float* __restrict__ g2,    // R x 384 (gh)
    float* __restrict__ h)           // R x 128, updated in place
{
    const int r0 = blockIdx.x * 32;
    __shared__ float a_t[32][36];    // [k][row], 144B rows: 16B aligned
    __shared__ float w_t[32][384];
    const int tid = threadIdx.x;
    const int cx = tid & 63;         // h-dim pair base
    const int ry = tid >> 6;         // row group (0..3)
    float bv[6];
#pragma unroll
    for (int j = 0; j < 6; ++j) bv[j] = bih[cx + 64*j];
    float acc[8][6];
#pragma unroll
    for (int i = 0; i < 8; ++i)
#pragma unroll
        for (int j = 0; j < 6; ++j) acc[i][j] = 0.f;

    for (int k0 = 0; k0 < HH; k0 += 32) {
        {
            int lr = tid >> 3, k4 = tid & 7;
            float4 v = *(const float4*)(xg + (size_t)(r0+lr)*HH + k0 + k4*4);
            a_t[k4*4+0][lr] = v.x; a_t[k4*4+1][lr] = v.y;
            a_t[k4*4+2][lr] = v.z; a_t[k4*4+3][lr] = v.w;
#pragma unroll
            for (int l = 0; l < 12; ++l) {
                int idx = tid + 256*l;          // 0..3071 float4s
                int wk = idx / 96, c4 = idx % 96;
                *(float4*)&w_t[wk][c4*4] =
                    *(const float4*)(Wih + (size_t)(k0+wk)*384 + c4*4);
            }
        }
        __syncthreads();
#pragma unroll 8
        for (int k = 0; k < 32; ++k) {
            float a[8];
            *(float4*)&a[0] = *(const float4*)&a_t[k][ry*8];
            *(float4*)&a[4] = *(const float4*)&a_t[k][ry*8+4];
            float b[6];
#pragma unroll
            for (int j = 0; j < 6; ++j) b[j] = w_t[k][cx + 64*j];
#pragma unroll
            for (int i = 0; i < 8; ++i)
#pragma unroll
                for (int j = 0; j < 6; ++j)
                    acc[i][j] = fmaf(a[i], b[j], acc[i][j]);
        }
        __syncthreads();
    }
    // gate epilogue: cols {cx, cx+64} of r/z/n gates for rows ry*8+i
#pragma unroll
    for (int i = 0; i < 8; ++i) {
        int row = r0 + ry*8 + i;
        const float* gr = g2 + (size_t)row*384;
        float* hp = h + (size_t)row*HH;
        float rx0 = acc[i][0]+bv[0], rx1 = acc[i][1]+bv[1];
        float zx0 = acc[i][2]+bv[2], zx1 = acc[i][3]+bv[3];
        float nx0 = acc[i][4]+bv[4], nx1 = acc[i][5]+bv[5];
        float rh0 = gr[cx],       rh1 = gr[cx+64];
        float zh0 = gr[128+cx],   zh1 = gr[128+cx+64];
        float nh0 = gr[256+cx],   nh1 = gr[256+cx+64];
        float h0 = hp[cx], h1 = hp[cx+64];
        float r_0 = sigmoidf_(rx0 + rh0), r_1 = sigmoidf_(rx1 + rh1);
        float z_0 = sigmoidf_(zx0 + zh0), z_1 = sigmoidf_(zx1 + zh1);
        float n_0 = tanhf(nx0 + r_0*nh0), n_1 = tanhf(nx1 + r_1*nh1);
        hp[cx]    = (1.f - z_0)*n_0 + z_0*h0;
        hp[cx+64] = (1.f - z_1)*n_1 + z_1*h1;
    }
}

// ---------------------------------------------------------------------------
// Kernel FC: xfc[r] = h[r] . W_fc + b_fc ; also writes d_out[b][p][n]
__global__ __launch_bounds__(256) void fck(
    const float* __restrict__ h,
    const float* __restrict__ Wfc, const float* __restrict__ bfc,
    float* __restrict__ out_p,   // d_out + p*NN
    float* __restrict__ xfc)
{
    int w = (blockIdx.x * 256 + threadIdx.x) >> 6;   // row
    int lane = threadIdx.x & 63;
    const float2* hr = (const float2*)(h + (size_t)w*HH);
    const float2* wf = (const float2*)Wfc;
    float2 a = hr[lane], b2 = wf[lane];
    float s = a.x*b2.x + a.y*b2.y;
#pragma unroll
    for (int off = 32; off; off >>= 1) s += __shfl_xor(s, off);
    if (lane == 0) {
        s += bfc[0];
        int n = w >> 5, b = w & 31;
        out_p[(size_t)b*(PP*NN) + n] = s;
        xfc[w] = s;
    }
}

// ---------------------------------------------------------------------------
extern "C" void kernel_launch(void* const* d_in, const int* in_sizes, int n_in,
                              void* d_out, int out_size, void* d_ws, size_t ws_size,
                              hipStream_t stream)
{
    const float* x    = (const float*)d_in[0];
    const float* adj  = (const float*)d_in[1];
    const float* Wg1  = (const float*)d_in[2];
    const float* bg1  = (const float*)d_in[3];
    const float* Wg2  = (const float*)d_in[4];
    const float* bg2  = (const float*)d_in[5];
    const float* Wih  = (const float*)d_in[6];
    const float* Whh  = (const float*)d_in[7];
    const float* bih  = (const float*)d_in[8];
    const float* bhh  = (const float*)d_in[9];
    const float* Wfc  = (const float*)d_in[10];
    const float* bfc  = (const float*)d_in[11];
    // pred_len (d_in[12]) is fixed at 3

    float* ws   = (float*)d_ws;
    const size_t R = RR;
    float* ax   = ws;                 // R
    float* xfc  = ws + R;             // R
    float* t1   = ws + 2*R;           // R*128
    float* xg   = t1 + R*HH;          // R*128
    float* hbuf = xg + R*HH;          // R*128
    float* g2   = hbuf + R*HH;        // R*384
    // total: R*770 floats ~= 192.5 MiB of d_ws

    hipMemsetAsync(hbuf, 0, R*HH*sizeof(float), stream);

    float* outp = (float*)d_out;

    auto cell = [&](const float* xt, int sb, int sn) {
        axk<<<RR/4, 256, 0, stream>>>(adj, xt, sb, sn, ax);
        t1k<<<RR/T1_ROWS, 256, 0, stream>>>(ax, Wg1, bg1, Wg2, t1);
        // xg = adj @ t1  (M=2048 nodes, Nc=4096 (b,h) cols, K=2048) + b_g2
        gemm_tile<<<dim3(32, 16), 256, 0, stream>>>(
            adj, NN, t1, NB*HH, xg, NB*HH, NN, bg2, HH);
        // g2 = h @ W_hh + b_hh  (M=65536, Nc=384, K=128)
        gemm_tile<<<dim3(3, RR/128), 256, 0, stream>>>(
            hbuf, HH, Whh, 3*HH, g2, 3*HH, HH, bhh, 3*HH);
        // gx + gates + h update (in place)
        gxgate<<<RR/32, 256, 0, stream>>>(xg, Wih, bih, g2, hbuf);
    };

    // encoder
    for (int t = 0; t < SS; ++t)
        cell(x + (size_t)t*NN, SS*NN, 1);
    // decoder: out_p = h @ W_fc, then cell(h, out_p); final cell is discarded
    for (int p = 0; p < PP; ++p) {
        fck<<<RR/4, 256, 0, stream>>>(hbuf, Wfc, bfc, outp + (size_t)p*NN, xfc);
        if (p < PP-1)
            cell(xfc, 1, NB);
    }
}

// Round 2
// 6421.567 us; speedup vs baseline: 1.5774x; 1.5774x over previous
//
#include <hip/hip_runtime.h>
#include <math.h>

// Problem constants: B=32, S=12, N=2048, F=1, H=128, G=64, O=1, P=3
#define NB 32
#define SS 12
#define NN 2048
#define HH 128
#define GG 64
#define PP 3
#define RR (NN*NB)   // 65536 rows, node-major r = n*32 + b

typedef __attribute__((ext_vector_type(8))) short short8;   // 8 bf16 (4 VGPRs)
typedef __attribute__((ext_vector_type(4))) float f32x4;

__device__ __forceinline__ unsigned short f2bf(float f) {   // RNE fp32->bf16
    unsigned b = __float_as_uint(f);
    return (unsigned short)((b + 0x7FFFu + ((b >> 16) & 1u)) >> 16);
}
__device__ __forceinline__ float bf2f(unsigned short u) {
    return __uint_as_float(((unsigned)u) << 16);
}
__device__ __forceinline__ void glds16(const void* g, const void* l) {
    __builtin_amdgcn_global_load_lds(
        (const __attribute__((address_space(1))) void*)g,
        (__attribute__((address_space(3))) void*)l, 16, 0, 0);
}

// ---------------------------------------------------------------------------
// ax[m*32+b] = sum_n adj[m][n] * xt[b*sb + n]   (both call sites use sn==1 now)
__global__ __launch_bounds__(256) void axk(
    const float* __restrict__ adj,
    const float* __restrict__ xt, int xt_sb,
    float* __restrict__ ax)
{
    int w = (blockIdx.x * 256 + threadIdx.x) >> 6;
    int lane = threadIdx.x & 63;
    int m = w >> 5, b = w & 31;
    const float4* arow = (const float4*)(adj + (size_t)m * NN);
    const float4* xrow = (const float4*)(xt + (size_t)b * xt_sb);
    float s = 0.f;
#pragma unroll
    for (int k = 0; k < 8; ++k) {
        float4 a4 = arow[lane + 64*k];
        float4 x4 = xrow[lane + 64*k];
        s += a4.x*x4.x + a4.y*x4.y + a4.z*x4.z + a4.w*x4.w;
    }
#pragma unroll
    for (int off = 32; off; off >>= 1) s += __shfl_xor(s, off);
    if (lane == 0) ax[(size_t)m*32 + b] = s;
}

// ---------------------------------------------------------------------------
// split fp32 -> bf16 hi + bf16 lo  (lo = bf16(x - fp32(hi)))
__global__ __launch_bounds__(256) void splitk(
    const float* __restrict__ src,
    unsigned short* __restrict__ hi, unsigned short* __restrict__ lo)
{
    size_t i0 = ((size_t)blockIdx.x * 256 + threadIdx.x) * 8;
    float4 v0 = *(const float4*)(src + i0);
    float4 v1 = *(const float4*)(src + i0 + 4);
    float f[8] = {v0.x,v0.y,v0.z,v0.w,v1.x,v1.y,v1.z,v1.w};
    union { unsigned short u[8]; uint4 q; } H, L;
#pragma unroll
    for (int k = 0; k < 8; ++k) {
        unsigned short h = f2bf(f[k]);
        H.u[k] = h;
        L.u[k] = f2bf(f[k] - bf2f(h));
    }
    *(uint4*)(hi + i0) = H.q;
    *(uint4*)(lo + i0) = L.q;
}

// ---------------------------------------------------------------------------
// t1 transposed + bf16-split: Bhi/Blo[col=(b*128+j)][k=n] with
// t1[n,b,j] = sum_g relu(ax[n*32+b]*W1[g]+b1[g]) * W2[g][j]
// grid: (NN/64, NB), 256 threads. Thread t: j=t&127, nh=t>>7 (32 n each).
__global__ __launch_bounds__(256) void t1kT(
    const float* __restrict__ ax,
    const float* __restrict__ Wg1, const float* __restrict__ bg1,
    const float* __restrict__ Wg2,                    // [64][128]
    unsigned short* __restrict__ Bhi, unsigned short* __restrict__ Blo)
{
    __shared__ float w2t[128][68];  // [j][g] transposed, padded
    __shared__ float rg[64][68];    // relu(a*w1+b1) per (n_loc, g)
    __shared__ float axs[64], w1s[64], b1s[64];
    const int tid = threadIdx.x;
    const int b = blockIdx.y;
    const int n0 = blockIdx.x * 64;
    if (tid < 64) {
        w1s[tid] = Wg1[tid]; b1s[tid] = bg1[tid];
        axs[tid] = ax[(size_t)(n0 + tid) * 32 + b];
    }
#pragma unroll
    for (int l = 0; l < 8; ++l) {
        int idx = tid + 256*l;               // 2048 float4 groups of W2
        int g = idx >> 5, j4 = (idx & 31) * 4;
        float4 v = *(const float4*)(Wg2 + g*HH + j4);
        w2t[j4+0][g] = v.x; w2t[j4+1][g] = v.y;
        w2t[j4+2][g] = v.z; w2t[j4+3][g] = v.w;
    }
    __syncthreads();
    {
        int n = tid >> 2, gq = (tid & 3) * 16;
        float a = axs[n];
#pragma unroll
        for (int gg = 0; gg < 16; gg += 4) {
            float4 v;
            v.x = fmaxf(fmaf(a, w1s[gq+gg+0], b1s[gq+gg+0]), 0.f);
            v.y = fmaxf(fmaf(a, w1s[gq+gg+1], b1s[gq+gg+1]), 0.f);
            v.z = fmaxf(fmaf(a, w1s[gq+gg+2], b1s[gq+gg+2]), 0.f);
            v.w = fmaxf(fmaf(a, w1s[gq+gg+3], b1s[gq+gg+3]), 0.f);
            *(float4*)&rg[n][gq+gg] = v;
        }
    }
    __syncthreads();
    const int j = tid & 127, nh = tid >> 7;
    float s[32];
#pragma unroll
    for (int i = 0; i < 32; ++i) s[i] = 0.f;
#pragma unroll 4
    for (int g4 = 0; g4 < 64; g4 += 4) {
        float4 w = *(float4*)&w2t[j][g4];
#pragma unroll
        for (int i = 0; i < 32; ++i) {
            float4 r4 = *(float4*)&rg[nh*32 + i][g4];   // wave-uniform broadcast
            s[i] = fmaf(w.x, r4.x, fmaf(w.y, r4.y,
                   fmaf(w.z, r4.z, fmaf(w.w, r4.w, s[i]))));
        }
    }
    size_t base = ((size_t)b*HH + j) * 2048 + n0 + nh*32;
#pragma unroll
    for (int c = 0; c < 4; ++c) {
        union { unsigned short u[8]; uint4 q; } H, L;
#pragma unroll
        for (int i = 0; i < 8; ++i) {
            float v = s[c*8 + i];
            unsigned short h = f2bf(v);
            H.u[i] = h;
            L.u[i] = f2bf(v - bf2f(h));
        }
        *(uint4*)(Bhi + base + c*8) = H.q;
        *(uint4*)(Blo + base + c*8) = L.q;
    }
}

// ---------------------------------------------------------------------------
// xg[2048][4096] = Ahi@Bhi^T + Alo@Bhi^T + Ahi@Blo^T + bias  (split-bf16 fp32-
// accurate GEMM). A[2048][2048], Bt[4096][2048] row-major bf16. m97 structure:
// 128x128 tile, BK=64, global_load_lds width 16, frag-order LDS, 16x16x32 MFMA.
__global__ __launch_bounds__(256) void gemm_mfma(
    const unsigned short* __restrict__ Ahi, const unsigned short* __restrict__ Alo,
    const unsigned short* __restrict__ Bhi, const unsigned short* __restrict__ Blo,
    float* __restrict__ C, const float* __restrict__ bias)
{
    __shared__ __align__(16) unsigned short As[8192];  // 16 tiles x 512 (16m x 32k)
    __shared__ __align__(16) unsigned short Bs[8192];
    const int tid  = threadIdx.x;
    const int wv   = tid >> 6, lane = tid & 63;
    const int lm   = lane & 15, lq = lane >> 4;
    const int m0   = blockIdx.y * 128;
    const int n0   = blockIdx.x * 128;
    const int wm   = wv >> 1, wn = wv & 1;    // 64x64 quadrant per wave

    f32x4 acc[4][4];
#pragma unroll
    for (int i = 0; i < 4; ++i)
#pragma unroll
        for (int j = 0; j < 4; ++j) acc[i][j] = (f32x4){0.f,0.f,0.f,0.f};

    for (int k0 = 0; k0 < 3*2048; k0 += 64) {
        const int kb = k0 >> 11;                       // split block 0,1,2
        const unsigned short* Ab = (kb == 1) ? Alo : Ahi;
        const unsigned short* Bb = (kb == 2) ? Blo : Bhi;
        const int kk = k0 & 2047;
#pragma unroll
        for (int t = 0; t < 4; ++t) {
            int tt = wv*4 + t;                         // tile 0..15
            int rt = tt >> 1, kt = tt & 1;             // row-tile, k-half
            const unsigned short* ga =
                Ab + (size_t)(m0 + rt*16 + lm)*2048 + kk + kt*32 + lq*8;
            glds16(ga, &As[tt*512]);
            const unsigned short* gb =
                Bb + (size_t)(n0 + rt*16 + lm)*2048 + kk + kt*32 + lq*8;
            glds16(gb, &Bs[tt*512]);
        }
        __syncthreads();
#pragma unroll
        for (int ks = 0; ks < 2; ++ks) {
            short8 af[4], bf[4];
#pragma unroll
            for (int i = 0; i < 4; ++i) {
                af[i] = *(const short8*)&As[((wm*4 + i)*2 + ks)*512 + lane*8];
                bf[i] = *(const short8*)&Bs[((wn*4 + i)*2 + ks)*512 + lane*8];
            }
#pragma unroll
            for (int i = 0; i < 4; ++i)
#pragma unroll
                for (int j = 0; j < 4; ++j)
                    acc[i][j] = __builtin_amdgcn_mfma_f32_16x16x32_bf16(
                        af[i], bf[j], acc[i][j], 0, 0, 0);
        }
        __syncthreads();
    }
    // C/D layout: col = lane&15, row = (lane>>4)*4 + reg  (m89/m91-verified)
#pragma unroll
    for (int i = 0; i < 4; ++i) {
        int row = m0 + wm*64 + i*16 + lq*4;
#pragma unroll
        for (int j = 0; j < 4; ++j) {
            int col = n0 + wn*64 + j*16 + lm;
            float bv = bias[col & (HH-1)];
            float* cp = C + (size_t)row*4096 + col;
            cp[0*4096] = acc[i][j][0] + bv;
            cp[1*4096] = acc[i][j][1] + bv;
            cp[2*4096] = acc[i][j][2] + bv;
            cp[3*4096] = acc[i][j][3] + bv;
        }
    }
}

// ---------------------------------------------------------------------------
// fp32 tiled GEMM (used for g2 = h @ W_hh + b_hh). 128x128 tile, 8x8 micro.
// b-fragment mapping split-halves (tx*4 and 64+tx*4): 2-way LDS aliasing = free.
__global__ __launch_bounds__(256) void gemm_tile(
    const float* __restrict__ A, int lda,
    const float* __restrict__ Bm, int ldb,
    float* __restrict__ C, int ldc,
    int K,
    const float* __restrict__ bias, int bias_period)
{
    const int m0 = blockIdx.y * 128;
    const int n0 = blockIdx.x * 128;
    __shared__ float a_t[32][132];
    __shared__ float b_t[32][132];
    const int tid = threadIdx.x;
    const int tx = tid & 15;
    const int ty = tid >> 4;
    float acc[8][8];
#pragma unroll
    for (int i = 0; i < 8; ++i)
#pragma unroll
        for (int j = 0; j < 8; ++j) acc[i][j] = 0.f;

    for (int k0 = 0; k0 < K; k0 += 32) {
        {
            int lrow = tid >> 3, lc4 = tid & 7;
#pragma unroll
            for (int p = 0; p < 4; ++p) {
                int row = lrow + p*32;
                float4 v = *(const float4*)(A + (size_t)(m0+row)*lda + k0 + lc4*4);
                a_t[lc4*4+0][row] = v.x; a_t[lc4*4+1][row] = v.y;
                a_t[lc4*4+2][row] = v.z; a_t[lc4*4+3][row] = v.w;
            }
            int brow = tid >> 5, bc4 = tid & 31;
#pragma unroll
            for (int p = 0; p < 4; ++p) {
                int kk = brow + p*8;
                float4 v = *(const float4*)(Bm + (size_t)(k0+kk)*ldb + n0 + bc4*4);
                *(float4*)&b_t[kk][bc4*4] = v;
            }
        }
        __syncthreads();
#pragma unroll 8
        for (int k = 0; k < 32; ++k) {
            float a[8], b[8];
            *(float4*)&a[0] = *(const float4*)&a_t[k][ty*8];
            *(float4*)&a[4] = *(const float4*)&a_t[k][ty*8+4];
            *(float4*)&b[0] = *(const float4*)&b_t[k][tx*4];
            *(float4*)&b[4] = *(const float4*)&b_t[k][64 + tx*4];
#pragma unroll
            for (int i = 0; i < 8; ++i)
#pragma unroll
                for (int j = 0; j < 8; ++j)
                    acc[i][j] = fmaf(a[i], b[j], acc[i][j]);
        }
        __syncthreads();
    }
    float bv[8];
#pragma unroll
    for (int j = 0; j < 4; ++j) {
        bv[j]   = bias ? bias[(n0 + tx*4 + j) % bias_period] : 0.f;
        bv[j+4] = bias ? bias[(n0 + 64 + tx*4 + j) % bias_period] : 0.f;
    }
#pragma unroll
    for (int i = 0; i < 8; ++i) {
        int row = m0 + ty*8 + i;
        float4 o0, o1;
        o0.x = acc[i][0]+bv[0]; o0.y = acc[i][1]+bv[1];
        o0.z = acc[i][2]+bv[2]; o0.w = acc[i][3]+bv[3];
        o1.x = acc[i][4]+bv[4]; o1.y = acc[i][5]+bv[5];
        o1.z = acc[i][6]+bv[6]; o1.w = acc[i][7]+bv[7];
        *(float4*)(C + (size_t)row*ldc + n0 + tx*4)      = o0;
        *(float4*)(C + (size_t)row*ldc + n0 + 64 + tx*4) = o1;
    }
}

// ---------------------------------------------------------------------------
// gx = xg_row @ W_ih + b_ih (32 rows/block), fused GRU gate update in place.
__device__ __forceinline__ float sigmoidf_(float x) {
    return 1.f / (1.f + __expf(-x));
}
__global__ __launch_bounds__(256) void gxgate(
    const float* __restrict__ xg,
    const float* __restrict__ Wih,   // 128 x 384
    const float* __restrict__ bih,   // 384
    const float* __restrict__ g2,    // R x 384 (gh)
    float* __restrict__ h)           // R x 128, updated in place
{
    const int r0 = blockIdx.x * 32;
    __shared__ float a_t[32][36];
    __shared__ float w_t[32][384];
    const int tid = threadIdx.x;
    const int cx = tid & 63;
    const int ry = tid >> 6;
    float bv[6];
#pragma unroll
    for (int j = 0; j < 6; ++j) bv[j] = bih[cx + 64*j];
    float acc[8][6];
#pragma unroll
    for (int i = 0; i < 8; ++i)
#pragma unroll
        for (int j = 0; j < 6; ++j) acc[i][j] = 0.f;

    for (int k0 = 0; k0 < HH; k0 += 32) {
        {
            int lr = tid >> 3, k4 = tid & 7;
            float4 v = *(const float4*)(xg + (size_t)(r0+lr)*HH + k0 + k4*4);
            a_t[k4*4+0][lr] = v.x; a_t[k4*4+1][lr] = v.y;
            a_t[k4*4+2][lr] = v.z; a_t[k4*4+3][lr] = v.w;
#pragma unroll
            for (int l = 0; l < 12; ++l) {
                int idx = tid + 256*l;
                int wk = idx / 96, c4 = idx % 96;
                *(float4*)&w_t[wk][c4*4] =
                    *(const float4*)(Wih + (size_t)(k0+wk)*384 + c4*4);
            }
        }
        __syncthreads();
#pragma unroll 8
        for (int k = 0; k < 32; ++k) {
            float a[8];
            *(float4*)&a[0] = *(const float4*)&a_t[k][ry*8];
            *(float4*)&a[4] = *(const float4*)&a_t[k][ry*8+4];
            float b[6];
#pragma unroll
            for (int j = 0; j < 6; ++j) b[j] = w_t[k][cx + 64*j];
#pragma unroll
            for (int i = 0; i < 8; ++i)
#pragma unroll
                for (int j = 0; j < 6; ++j)
                    acc[i][j] = fmaf(a[i], b[j], acc[i][j]);
        }
        __syncthreads();
    }
#pragma unroll
    for (int i = 0; i < 8; ++i) {
        int row = r0 + ry*8 + i;
        const float* gr = g2 + (size_t)row*384;
        float* hp = h + (size_t)row*HH;
        float rx0 = acc[i][0]+bv[0], rx1 = acc[i][1]+bv[1];
        float zx0 = acc[i][2]+bv[2], zx1 = acc[i][3]+bv[3];
        float nx0 = acc[i][4]+bv[4], nx1 = acc[i][5]+bv[5];
        float rh0 = gr[cx],       rh1 = gr[cx+64];
        float zh0 = gr[128+cx],   zh1 = gr[128+cx+64];
        float nh0 = gr[256+cx],   nh1 = gr[256+cx+64];
        float h0 = hp[cx], h1 = hp[cx+64];
        float r_0 = sigmoidf_(rx0 + rh0), r_1 = sigmoidf_(rx1 + rh1);
        float z_0 = sigmoidf_(zx0 + zh0), z_1 = sigmoidf_(zx1 + zh1);
        float n_0 = tanhf(nx0 + r_0*nh0), n_1 = tanhf(nx1 + r_1*nh1);
        hp[cx]    = (1.f - z_0)*n_0 + z_0*h0;
        hp[cx+64] = (1.f - z_1)*n_1 + z_1*h1;
    }
}

// ---------------------------------------------------------------------------
// xfc[b][n] = h[r] . W_fc + b_fc ; also writes d_out[b][p][n]
__global__ __launch_bounds__(256) void fck(
    const float* __restrict__ h,
    const float* __restrict__ Wfc, const float* __restrict__ bfc,
    float* __restrict__ out_p,
    float* __restrict__ xfc)
{
    int w = (blockIdx.x * 256 + threadIdx.x) >> 6;
    int lane = threadIdx.x & 63;
    const float2* hr = (const float2*)(h + (size_t)w*HH);
    const float2* wf = (const float2*)Wfc;
    float2 a = hr[lane], b2 = wf[lane];
    float s = a.x*b2.x + a.y*b2.y;
#pragma unroll
    for (int off = 32; off; off >>= 1) s += __shfl_xor(s, off);
    if (lane == 0) {
        s += bfc[0];
        int n = w >> 5, b = w & 31;
        out_p[(size_t)b*(PP*NN) + n] = s;
        xfc[(size_t)b*NN + n] = s;   // [b][n]: decoder axk takes coalesced path
    }
}

// ---------------------------------------------------------------------------
extern "C" void kernel_launch(void* const* d_in, const int* in_sizes, int n_in,
                              void* d_out, int out_size, void* d_ws, size_t ws_size,
                              hipStream_t stream)
{
    const float* x    = (const float*)d_in[0];
    const float* adj  = (const float*)d_in[1];
    const float* Wg1  = (const float*)d_in[2];
    const float* bg1  = (const float*)d_in[3];
    const float* Wg2  = (const float*)d_in[4];
    const float* bg2  = (const float*)d_in[5];
    const float* Wih  = (const float*)d_in[6];
    const float* Whh  = (const float*)d_in[7];
    const float* bih  = (const float*)d_in[8];
    const float* bhh  = (const float*)d_in[9];
    const float* Wfc  = (const float*)d_in[10];
    const float* bfc  = (const float*)d_in[11];

    float* ws   = (float*)d_ws;
    const size_t R = RR;
    float* ax   = ws;                          // R
    float* xfc  = ax + R;                      // R  ([b][n] layout)
    float* xg   = xfc + R;                     // R*128
    float* hbuf = xg + R*HH;                   // R*128
    // g2 (R*384 fp32, 96 MB) time-shares memory with Bhi/Blo (48 MB):
    // t1kT writes B -> gemm_mfma reads B -> gemm_tile writes g2 (B dead) ->
    // gxgate reads g2 -> next t1kT overwrites (g2 dead).
    float* g2f  = hbuf + R*HH;
    unsigned short* Bhi = (unsigned short*)g2f;            // 4096*2048
    unsigned short* Blo = Bhi + (size_t)4096*2048;
    unsigned short* Ahi = (unsigned short*)(g2f + R*384);  // 2048*2048
    unsigned short* Alo = Ahi + (size_t)2048*2048;
    // total ws use: ~176.5 MiB (< round-1's 192.5 MiB)

    hipMemsetAsync(hbuf, 0, R*HH*sizeof(float), stream);
    splitk<<<2048, 256, 0, stream>>>(adj, Ahi, Alo);       // adj -> bf16 hi/lo

    float* outp = (float*)d_out;

    auto cell = [&](const float* xt, int sb) {
        axk<<<RR/4, 256, 0, stream>>>(adj, xt, sb, ax);
        t1kT<<<dim3(NN/64, NB), 256, 0, stream>>>(ax, Wg1, bg1, Wg2, Bhi, Blo);
        gemm_mfma<<<dim3(32, 16), 256, 0, stream>>>(Ahi, Alo, Bhi, Blo, xg, bg2);
        gemm_tile<<<dim3(3, RR/128), 256, 0, stream>>>(
            hbuf, HH, Whh, 3*HH, g2f, 3*HH, HH, bhh, 3*HH);
        gxgate<<<RR/32, 256, 0, stream>>>(xg, Wih, bih, g2f, hbuf);
    };

    for (int t = 0; t < SS; ++t)
        cell(x + (size_t)t*NN, SS*NN);
    for (int p = 0; p < PP; ++p) {
        fck<<<RR/4, 256, 0, stream>>>(hbuf, Wfc, bfc, outp + (size_t)p*NN, xfc);
        if (p < PP-1)
            cell(xfc, NN);
    }
}

// Round 3
// 4012.778 us; speedup vs baseline: 2.5242x; 1.6003x over previous
//
#include <hip/hip_runtime.h>
#include <math.h>

// Problem constants: B=32, S=12, N=2048, F=1, H=128, G=64, O=1, P=3
#define NB 32
#define SS 12
#define NN 2048
#define HH 128
#define GG 64
#define PP 3
#define RR (NN*NB)   // 65536 rows, node-major r = n*32 + b

typedef __attribute__((ext_vector_type(8))) short short8;   // 8 bf16 (4 VGPRs)
typedef __attribute__((ext_vector_type(4))) float f32x4;

__device__ __forceinline__ unsigned short f2bf(float f) {   // RNE fp32->bf16
    unsigned b = __float_as_uint(f);
    return (unsigned short)((b + 0x7FFFu + ((b >> 16) & 1u)) >> 16);
}
__device__ __forceinline__ float bf2f(unsigned short u) {
    return __uint_as_float(((unsigned)u) << 16);
}
__device__ __forceinline__ void glds16(const void* g, const void* l) {
    __builtin_amdgcn_global_load_lds(
        (const __attribute__((address_space(1))) void*)g,
        (__attribute__((address_space(3))) void*)l, 16, 0, 0);
}

// ---------------------------------------------------------------------------
// ax[t][b][m] = sum_n adj[m][n] * x[t,b-row n]; one wave per (t,m,b).
__global__ __launch_bounds__(256) void axk(
    const float* __restrict__ adj,
    const float* __restrict__ xbase, int tstride, int sb,
    float* __restrict__ out)
{
    int w = (blockIdx.x * 256 + threadIdx.x) >> 6;
    int lane = threadIdx.x & 63;
    int m = w >> 5, b = w & 31;
    const float* xt = xbase + (size_t)blockIdx.y * tstride;
    const float4* arow = (const float4*)(adj + (size_t)m * NN);
    const float4* xrow = (const float4*)(xt + (size_t)b * sb);
    float s = 0.f;
#pragma unroll
    for (int k = 0; k < 8; ++k) {
        float4 a4 = arow[lane + 64*k];
        float4 x4 = xrow[lane + 64*k];
        s += a4.x*x4.x + a4.y*x4.y + a4.z*x4.z + a4.w*x4.w;
    }
#pragma unroll
    for (int off = 32; off; off >>= 1) s += __shfl_xor(s, off);
    if (lane == 0)
        out[((size_t)blockIdx.y * NB + b) * NN + m] = s;   // [t][b][m]
}

// ---------------------------------------------------------------------------
// split fp32 -> bf16 hi + bf16 lo  (lo = bf16(x - fp32(hi)))
__global__ __launch_bounds__(256) void splitk(
    const float* __restrict__ src,
    unsigned short* __restrict__ hi, unsigned short* __restrict__ lo)
{
    size_t i0 = ((size_t)blockIdx.x * 256 + threadIdx.x) * 8;
    float4 v0 = *(const float4*)(src + i0);
    float4 v1 = *(const float4*)(src + i0 + 4);
    float f[8] = {v0.x,v0.y,v0.z,v0.w,v1.x,v1.y,v1.z,v1.w};
    union { unsigned short u[8]; uint4 q; } H, L;
#pragma unroll
    for (int k = 0; k < 8; ++k) {
        unsigned short h = f2bf(f[k]);
        H.u[k] = h;
        L.u[k] = f2bf(f[k] - bf2f(h));
    }
    *(uint4*)(hi + i0) = H.q;
    *(uint4*)(lo + i0) = L.q;
}

// ---------------------------------------------------------------------------
// Precompute Wc[64][384] = Wg2 @ Wih and bc[384] = bg2 @ Wih + bih.
__global__ __launch_bounds__(256) void wprep(
    const float* __restrict__ Wg2, const float* __restrict__ Wih,
    const float* __restrict__ bih, const float* __restrict__ bg2,
    float* __restrict__ Wc, float* __restrict__ bc)
{
    int idx = blockIdx.x * 256 + threadIdx.x;
    if (idx < GG*384) {
        int g = idx / 384, o = idx % 384;
        float s = 0.f;
        for (int k = 0; k < HH; ++k)
            s = fmaf(Wg2[g*HH + k], Wih[k*384 + o], s);
        Wc[idx] = s;
    } else if (idx < GG*384 + 384) {
        int o = idx - GG*384;
        float s = bih[o];
        for (int k = 0; k < HH; ++k)
            s = fmaf(bg2[k], Wih[k*384 + o], s);
        bc[o] = s;
    }
}

// ---------------------------------------------------------------------------
// h1 transposed + bf16-split: H[col=b*64+g][n] = relu(axb[b][n]*W1[g]+b1[g]).
// grid 2048 blocks (one col each), 256 threads x 8 n.
__global__ __launch_bounds__(256) void h1T(
    const float* __restrict__ axb,    // [32][2048] for this step
    const float* __restrict__ Wg1, const float* __restrict__ bg1,
    unsigned short* __restrict__ Hhi, unsigned short* __restrict__ Hlo)
{
    const int c = blockIdx.x;
    const int b = c >> 6, g = c & 63;
    const float w1 = Wg1[g], b1 = bg1[g];
    const int t = threadIdx.x;
    float4 v0 = *(const float4*)(axb + (size_t)b*NN + t*8);
    float4 v1 = *(const float4*)(axb + (size_t)b*NN + t*8 + 4);
    float f[8] = {v0.x,v0.y,v0.z,v0.w,v1.x,v1.y,v1.z,v1.w};
    union { unsigned short u[8]; uint4 q; } H, L;
#pragma unroll
    for (int k = 0; k < 8; ++k) {
        float v = fmaxf(fmaf(f[k], w1, b1), 0.f);
        unsigned short h = f2bf(v);
        H.u[k] = h;
        L.u[k] = f2bf(v - bf2f(h));
    }
    *(uint4*)(Hhi + (size_t)c*NN + t*8) = H.q;
    *(uint4*)(Hlo + (size_t)c*NN + t*8) = L.q;
}

// ---------------------------------------------------------------------------
// z = adj @ h1 with split-bf16 (Ahi@Bhi + Alo@Bhi + Ahi@Blo), M=N=2048,
// K=3*2048 reading split blocks. Split-K=2 via blockIdx.z -> zp[z] partials.
// m97 structure: 128x128 tile, BK=64, global_load_lds 16B, 16x16x32 MFMA.
__global__ __launch_bounds__(256) void gemm_mfma(
    const unsigned short* __restrict__ Ahi, const unsigned short* __restrict__ Alo,
    const unsigned short* __restrict__ Bhi, const unsigned short* __restrict__ Blo,
    float* __restrict__ Cpart)
{
    __shared__ __align__(16) unsigned short As[8192];  // 16 tiles x (16m x 32k)
    __shared__ __align__(16) unsigned short Bs[8192];
    const int tid  = threadIdx.x;
    const int wv   = tid >> 6, lane = tid & 63;
    const int lm   = lane & 15, lq = lane >> 4;
    const int m0   = blockIdx.y * 128;
    const int n0   = blockIdx.x * 128;
    const int wm   = wv >> 1, wn = wv & 1;
    float* C = Cpart + (size_t)blockIdx.z * NN * NN;

    f32x4 acc[4][4];
#pragma unroll
    for (int i = 0; i < 4; ++i)
#pragma unroll
        for (int j = 0; j < 4; ++j) acc[i][j] = (f32x4){0.f,0.f,0.f,0.f};

    const int kbeg = blockIdx.z * 3072, kend = kbeg + 3072;
    for (int k0 = kbeg; k0 < kend; k0 += 64) {
        const int kb = k0 >> 11;                       // split term 0,1,2
        const unsigned short* Ab = (kb == 1) ? Alo : Ahi;
        const unsigned short* Bb = (kb == 2) ? Blo : Bhi;
        const int kk = k0 & 2047;
#pragma unroll
        for (int t = 0; t < 4; ++t) {
            int tt = wv*4 + t;
            int rt = tt >> 1, kt = tt & 1;
            const unsigned short* ga =
                Ab + (size_t)(m0 + rt*16 + lm)*2048 + kk + kt*32 + lq*8;
            glds16(ga, &As[tt*512]);
            const unsigned short* gb =
                Bb + (size_t)(n0 + rt*16 + lm)*2048 + kk + kt*32 + lq*8;
            glds16(gb, &Bs[tt*512]);
        }
        __syncthreads();
#pragma unroll
        for (int ks = 0; ks < 2; ++ks) {
            short8 af[4], bf[4];
#pragma unroll
            for (int i = 0; i < 4; ++i) {
                af[i] = *(const short8*)&As[((wm*4 + i)*2 + ks)*512 + lane*8];
                bf[i] = *(const short8*)&Bs[((wn*4 + i)*2 + ks)*512 + lane*8];
            }
#pragma unroll
            for (int i = 0; i < 4; ++i)
#pragma unroll
                for (int j = 0; j < 4; ++j)
                    acc[i][j] = __builtin_amdgcn_mfma_f32_16x16x32_bf16(
                        af[i], bf[j], acc[i][j], 0, 0, 0);
        }
        __syncthreads();
    }
    // C/D layout: col = lane&15, row = (lane>>4)*4 + reg
#pragma unroll
    for (int i = 0; i < 4; ++i) {
        int row = m0 + wm*64 + i*16 + lq*4;
#pragma unroll
        for (int j = 0; j < 4; ++j) {
            int col = n0 + wn*64 + j*16 + lm;
            float* cp = C + (size_t)row*NN + col;
            cp[0*NN] = acc[i][j][0];
            cp[1*NN] = acc[i][j][1];
            cp[2*NN] = acc[i][j][2];
            cp[3*NN] = acc[i][j][3];
        }
    }
}

// ---------------------------------------------------------------------------
// Fused gate kernel: per block (node m, 32 batch rows):
//   gatesX = z_row @ Wc[64][384] + bc      (z row = zp0+zp1, cols b*64+g)
//   gatesH = h @ Whh[128][384] + bhh
//   r = sig(Xr+Hr), zg = sig(Xz+Hz), n = tanh(Xn + r*Hn), h' = (1-zg)n + zg h
__device__ __forceinline__ float sigmoidf_(float x) {
    return 1.f / (1.f + __expf(-x));
}
__global__ __launch_bounds__(256) void gxgate(
    const float* __restrict__ zp0, const float* __restrict__ zp1,
    const float* __restrict__ Wc,  const float* __restrict__ bc,
    const float* __restrict__ Whh, const float* __restrict__ bhh,
    float* __restrict__ h)           // R x 128, updated in place
{
    const int m  = blockIdx.x;
    const int r0 = m * 32;
    __shared__ float zt[64][36];     // [g][b]
    __shared__ float a_t[32][36];    // [k][row]
    __shared__ float w_t[32][384];
    const int tid = threadIdx.x;
    const int cx = tid & 63;
    const int ry = tid >> 6;
    float bcv[6], bhv[6];
#pragma unroll
    for (int j = 0; j < 6; ++j) { bcv[j] = bc[cx + 64*j]; bhv[j] = bhh[cx + 64*j]; }

    {   // stage z row (sum of split-K partials), transpose to [g][b]
        const float4* z0 = (const float4*)(zp0 + (size_t)m*NN);
        const float4* z1 = (const float4*)(zp1 + (size_t)m*NN);
        float4 u0 = z0[tid*2], u1 = z0[tid*2+1];
        float4 w0 = z1[tid*2], w1 = z1[tid*2+1];
        int b = tid >> 3, g0 = (tid & 7) * 8;
        zt[g0+0][b] = u0.x+w0.x; zt[g0+1][b] = u0.y+w0.y;
        zt[g0+2][b] = u0.z+w0.z; zt[g0+3][b] = u0.w+w0.w;
        zt[g0+4][b] = u1.x+w1.x; zt[g0+5][b] = u1.y+w1.y;
        zt[g0+6][b] = u1.z+w1.z; zt[g0+7][b] = u1.w+w1.w;
    }
    float accx[8][6], acch[8][6];
#pragma unroll
    for (int i = 0; i < 8; ++i)
#pragma unroll
        for (int j = 0; j < 6; ++j) { accx[i][j] = 0.f; acch[i][j] = 0.f; }

    // phase 1: K=64 over Wc (x-path)
    for (int k0 = 0; k0 < 64; k0 += 32) {
#pragma unroll
        for (int l = 0; l < 12; ++l) {
            int idx = tid + 256*l;
            int wk = idx / 96, c4 = idx % 96;
            *(float4*)&w_t[wk][c4*4] =
                *(const float4*)(Wc + (size_t)(k0+wk)*384 + c4*4);
        }
        __syncthreads();
#pragma unroll 8
        for (int k = 0; k < 32; ++k) {
            float a[8];
            *(float4*)&a[0] = *(const float4*)&zt[k0+k][ry*8];
            *(float4*)&a[4] = *(const float4*)&zt[k0+k][ry*8+4];
            float b[6];
#pragma unroll
            for (int j = 0; j < 6; ++j) b[j] = w_t[k][cx + 64*j];
#pragma unroll
            for (int i = 0; i < 8; ++i)
#pragma unroll
                for (int j = 0; j < 6; ++j)
                    accx[i][j] = fmaf(a[i], b[j], accx[i][j]);
        }
        __syncthreads();
    }
    // phase 2: K=128 over Whh (h-path)
    for (int k0 = 0; k0 < HH; k0 += 32) {
        {
            int lr = tid >> 3, k4 = tid & 7;
            float4 v = *(const float4*)(h + (size_t)(r0+lr)*HH + k0 + k4*4);
            a_t[k4*4+0][lr] = v.x; a_t[k4*4+1][lr] = v.y;
            a_t[k4*4+2][lr] = v.z; a_t[k4*4+3][lr] = v.w;
#pragma unroll
            for (int l = 0; l < 12; ++l) {
                int idx = tid + 256*l;
                int wk = idx / 96, c4 = idx % 96;
                *(float4*)&w_t[wk][c4*4] =
                    *(const float4*)(Whh + (size_t)(k0+wk)*384 + c4*4);
            }
        }
        __syncthreads();
#pragma unroll 8
        for (int k = 0; k < 32; ++k) {
            float a[8];
            *(float4*)&a[0] = *(const float4*)&a_t[k][ry*8];
            *(float4*)&a[4] = *(const float4*)&a_t[k][ry*8+4];
            float b[6];
#pragma unroll
            for (int j = 0; j < 6; ++j) b[j] = w_t[k][cx + 64*j];
#pragma unroll
            for (int i = 0; i < 8; ++i)
#pragma unroll
                for (int j = 0; j < 6; ++j)
                    acch[i][j] = fmaf(a[i], b[j], acch[i][j]);
        }
        __syncthreads();
    }
    // epilogue: cols {cx, cx+64} of r/z/n for rows ry*8+i
#pragma unroll
    for (int i = 0; i < 8; ++i) {
        int row = r0 + ry*8 + i;
        float* hp = h + (size_t)row*HH;
        float rx0 = accx[i][0]+bcv[0], rx1 = accx[i][1]+bcv[1];
        float zx0 = accx[i][2]+bcv[2], zx1 = accx[i][3]+bcv[3];
        float nx0 = accx[i][4]+bcv[4], nx1 = accx[i][5]+bcv[5];
        float rh0 = acch[i][0]+bhv[0], rh1 = acch[i][1]+bhv[1];
        float zh0 = acch[i][2]+bhv[2], zh1 = acch[i][3]+bhv[3];
        float nh0 = acch[i][4]+bhv[4], nh1 = acch[i][5]+bhv[5];
        float h0 = hp[cx], h1 = hp[cx+64];
        float r_0 = sigmoidf_(rx0 + rh0), r_1 = sigmoidf_(rx1 + rh1);
        float z_0 = sigmoidf_(zx0 + zh0), z_1 = sigmoidf_(zx1 + zh1);
        float n_0 = tanhf(nx0 + r_0*nh0), n_1 = tanhf(nx1 + r_1*nh1);
        hp[cx]    = (1.f - z_0)*n_0 + z_0*h0;
        hp[cx+64] = (1.f - z_1)*n_1 + z_1*h1;
    }
}

// ---------------------------------------------------------------------------
// xfc[b][n] = h[r] . W_fc + b_fc ; also writes d_out[b][p][n]
__global__ __launch_bounds__(256) void fck(
    const float* __restrict__ h,
    const float* __restrict__ Wfc, const float* __restrict__ bfc,
    float* __restrict__ out_p,
    float* __restrict__ xfc)
{
    int w = (blockIdx.x * 256 + threadIdx.x) >> 6;
    int lane = threadIdx.x & 63;
    const float2* hr = (const float2*)(h + (size_t)w*HH);
    const float2* wf = (const float2*)Wfc;
    float2 a = hr[lane], b2 = wf[lane];
    float s = a.x*b2.x + a.y*b2.y;
#pragma unroll
    for (int off = 32; off; off >>= 1) s += __shfl_xor(s, off);
    if (lane == 0) {
        s += bfc[0];
        int n = w >> 5, b = w & 31;
        out_p[(size_t)b*(PP*NN) + n] = s;
        xfc[(size_t)b*NN + n] = s;
    }
}

// ---------------------------------------------------------------------------
extern "C" void kernel_launch(void* const* d_in, const int* in_sizes, int n_in,
                              void* d_out, int out_size, void* d_ws, size_t ws_size,
                              hipStream_t stream)
{
    const float* x    = (const float*)d_in[0];
    const float* adj  = (const float*)d_in[1];
    const float* Wg1  = (const float*)d_in[2];
    const float* bg1  = (const float*)d_in[3];
    const float* Wg2  = (const float*)d_in[4];
    const float* bg2  = (const float*)d_in[5];
    const float* Wih  = (const float*)d_in[6];
    const float* Whh  = (const float*)d_in[7];
    const float* bih  = (const float*)d_in[8];
    const float* bhh  = (const float*)d_in[9];
    const float* Wfc  = (const float*)d_in[10];
    const float* bfc  = (const float*)d_in[11];

    float* ws = (float*)d_ws;
    float* ax2  = ws;                         // 12*32*2048
    float* axd  = ax2 + (size_t)SS*NB*NN;     // 32*2048
    float* xfc  = axd + (size_t)NB*NN;        // 32*2048 ([b][n])
    float* hbuf = xfc + (size_t)NB*NN;        // R*128
    float* zp0  = hbuf + (size_t)RR*HH;       // 2048*2048 (split-K partial 0)
    float* zp1  = zp0 + (size_t)NN*NN;        // partial 1
    float* Wc   = zp1 + (size_t)NN*NN;        // 64*384
    float* bc   = Wc + GG*384;                // 384 (+pad)
    unsigned short* Ahi = (unsigned short*)(bc + 1024);
    unsigned short* Alo = Ahi + (size_t)NN*NN;
    unsigned short* Hhi = Alo + (size_t)NN*NN;
    unsigned short* Hlo = Hhi + (size_t)NN*NN;
    // total ws use ~104 MiB

    hipMemsetAsync(hbuf, 0, (size_t)RR*HH*sizeof(float), stream);
    splitk<<<2048, 256, 0, stream>>>(adj, Ahi, Alo);
    wprep<<<98, 256, 0, stream>>>(Wg2, Wih, bih, bg2, Wc, bc);
    // all 12 encoder ax in one dispatch: ax2[t][b][m]
    axk<<<dim3(RR/4, SS), 256, 0, stream>>>(adj, x, NN, SS*NN, ax2);

    float* outp = (float*)d_out;

    auto cell = [&](const float* axb) {
        h1T<<<2048, 256, 0, stream>>>(axb, Wg1, bg1, Hhi, Hlo);
        gemm_mfma<<<dim3(16, 16, 2), 256, 0, stream>>>(Ahi, Alo, Hhi, Hlo, zp0);
        gxgate<<<NN, 256, 0, stream>>>(zp0, zp1, Wc, bc, Whh, bhh, hbuf);
    };

    for (int t = 0; t < SS; ++t)
        cell(ax2 + (size_t)t*NB*NN);
    for (int p = 0; p < PP; ++p) {
        fck<<<RR/4, 256, 0, stream>>>(hbuf, Wfc, bfc, outp + (size_t)p*NN, xfc);
        if (p < PP-1) {
            axk<<<dim3(RR/4, 1), 256, 0, stream>>>(adj, xfc, 0, NN, axd);
            cell(axd);
        }
    }
}

// Round 4
// 3950.184 us; speedup vs baseline: 2.5642x; 1.0158x over previous
//
#include <hip/hip_runtime.h>
#include <math.h>

// Problem constants: B=32, S=12, N=2048, F=1, H=128, G=64, O=1, P=3
#define NB 32
#define SS 12
#define NN 2048
#define HH 128
#define GG 64
#define PP 3
#define RR (NN*NB)   // 65536 rows, node-major r = n*32 + b

typedef __attribute__((ext_vector_type(8))) short short8;   // 8 bf16 (4 VGPRs)
typedef __attribute__((ext_vector_type(4))) float f32x4;

__device__ __forceinline__ unsigned short f2bf(float f) {   // RNE fp32->bf16
    unsigned b = __float_as_uint(f);
    return (unsigned short)((b + 0x7FFFu + ((b >> 16) & 1u)) >> 16);
}
__device__ __forceinline__ float bf2f(unsigned short u) {
    return __uint_as_float(((unsigned)u) << 16);
}
__device__ __forceinline__ void glds16(const void* g, const void* l) {
    __builtin_amdgcn_global_load_lds(
        (const __attribute__((address_space(1))) void*)g,
        (__attribute__((address_space(3))) void*)l, 16, 0, 0);
}

// ---------------------------------------------------------------------------
// split fp32 -> bf16 hi + bf16 lo  (lo = bf16(x - fp32(hi)))
__global__ __launch_bounds__(256) void splitk(
    const float* __restrict__ src,
    unsigned short* __restrict__ hi, unsigned short* __restrict__ lo)
{
    size_t i0 = ((size_t)blockIdx.x * 256 + threadIdx.x) * 8;
    float4 v0 = *(const float4*)(src + i0);
    float4 v1 = *(const float4*)(src + i0 + 4);
    float f[8] = {v0.x,v0.y,v0.z,v0.w,v1.x,v1.y,v1.z,v1.w};
    union { unsigned short u[8]; uint4 q; } H, L;
#pragma unroll
    for (int k = 0; k < 8; ++k) {
        unsigned short h = f2bf(f[k]);
        H.u[k] = h;
        L.u[k] = f2bf(f[k] - bf2f(h));
    }
    *(uint4*)(hi + i0) = H.q;
    *(uint4*)(lo + i0) = L.q;
}

// ---------------------------------------------------------------------------
// Encoder x -> split rows [(t*32+b)][n] from x[b][t][n]. 384 blocks.
__global__ __launch_bounds__(256) void xsplit_enc(
    const float* __restrict__ x,
    unsigned short* __restrict__ hi, unsigned short* __restrict__ lo)
{
    const int row = blockIdx.x;            // t*32 + b
    const int t = row >> 5, b = row & 31;
    const size_t n0 = (size_t)threadIdx.x * 8;
    const float* src = x + ((size_t)b*SS + t)*NN;
    float4 v0 = *(const float4*)(src + n0);
    float4 v1 = *(const float4*)(src + n0 + 4);
    float f[8] = {v0.x,v0.y,v0.z,v0.w,v1.x,v1.y,v1.z,v1.w};
    union { unsigned short u[8]; uint4 q; } H, L;
#pragma unroll
    for (int k = 0; k < 8; ++k) {
        unsigned short h = f2bf(f[k]);
        H.u[k] = h;
        L.u[k] = f2bf(f[k] - bf2f(h));
    }
    *(uint4*)(hi + (size_t)row*NN + n0) = H.q;
    *(uint4*)(lo + (size_t)row*NN + n0) = L.q;
}

// Decoder xfc[b][n] -> split rows [b][n] (rows 32..127 pre-zeroed). 32 blocks.
__global__ __launch_bounds__(256) void xsplit_dec(
    const float* __restrict__ xfc,
    unsigned short* __restrict__ hi, unsigned short* __restrict__ lo)
{
    const int b = blockIdx.x;
    const size_t n0 = (size_t)threadIdx.x * 8;
    const float* src = xfc + (size_t)b*NN;
    float4 v0 = *(const float4*)(src + n0);
    float4 v1 = *(const float4*)(src + n0 + 4);
    float f[8] = {v0.x,v0.y,v0.z,v0.w,v1.x,v1.y,v1.z,v1.w};
    union { unsigned short u[8]; uint4 q; } H, L;
#pragma unroll
    for (int k = 0; k < 8; ++k) {
        unsigned short h = f2bf(f[k]);
        H.u[k] = h;
        L.u[k] = f2bf(f[k] - bf2f(h));
    }
    *(uint4*)(hi + (size_t)b*NN + n0) = H.q;
    *(uint4*)(lo + (size_t)b*NN + n0) = L.q;
}

// ---------------------------------------------------------------------------
// Precompute Wc[64][384] = Wg2 @ Wih and bc[384] = bg2 @ Wih + bih.
__global__ __launch_bounds__(256) void wprep(
    const float* __restrict__ Wg2, const float* __restrict__ Wih,
    const float* __restrict__ bih, const float* __restrict__ bg2,
    float* __restrict__ Wc, float* __restrict__ bc)
{
    int idx = blockIdx.x * 256 + threadIdx.x;
    if (idx < GG*384) {
        int g = idx / 384, o = idx % 384;
        float s = 0.f;
        for (int k = 0; k < HH; ++k)
            s = fmaf(Wg2[g*HH + k], Wih[k*384 + o], s);
        Wc[idx] = s;
    } else if (idx < GG*384 + 384) {
        int o = idx - GG*384;
        float s = bih[o];
        for (int k = 0; k < HH; ++k)
            s = fmaf(bg2[k], Wih[k*384 + o], s);
        bc[o] = s;
    }
}

// ---------------------------------------------------------------------------
// h1 from ax partials: H[(ty*2048 + c)][n] = relu(ax[.]*W1[g]+b1[g]) split,
// c = b*64+g; ax row in AX-part buffer = col_base + ty*32 + b, summed over
// 4 split-K partials (part_stride apart). grid (2048, nt).
__global__ __launch_bounds__(256) void h1T(
    const float* __restrict__ axpart, int col_base, size_t part_stride,
    const float* __restrict__ Wg1, const float* __restrict__ bg1,
    unsigned short* __restrict__ Hhi, unsigned short* __restrict__ Hlo)
{
    const int c = blockIdx.x;
    const int ty = blockIdx.y;
    const int b = c >> 6, g = c & 63;
    const float w1 = Wg1[g], b1 = bg1[g];
    const size_t n0 = (size_t)threadIdx.x * 8;
    const size_t rowoff = (size_t)(col_base + ty*32 + b) * NN + n0;
    float f[8] = {0,0,0,0,0,0,0,0};
#pragma unroll
    for (int p = 0; p < 4; ++p) {
        const float4* q = (const float4*)(axpart + p*part_stride + rowoff);
        float4 v0 = q[0], v1 = q[1];
        f[0]+=v0.x; f[1]+=v0.y; f[2]+=v0.z; f[3]+=v0.w;
        f[4]+=v1.x; f[5]+=v1.y; f[6]+=v1.z; f[7]+=v1.w;
    }
    union { unsigned short u[8]; uint4 q; } H, L;
#pragma unroll
    for (int k = 0; k < 8; ++k) {
        float v = fmaxf(fmaf(f[k], w1, b1), 0.f);
        unsigned short h = f2bf(v);
        H.u[k] = h;
        L.u[k] = f2bf(v - bf2f(h));
    }
    size_t base = ((size_t)ty*2048 + c) * NN + n0;
    *(uint4*)(Hhi + base) = H.q;
    *(uint4*)(Hlo + base) = L.q;
}

// ---------------------------------------------------------------------------
// Split-bf16 MFMA GEMM core (Ahi@Bhi + Alo@Bhi + Ahi@Blo over K=3*2048).
// A rows = m (2048, k-stride 2048); B rows = output cols (k-stride 2048).
// 128x128 tile, BK=64, global_load_lds 16B, 16x16x32 MFMA.
#define GEMM_BODY                                                              \
    __shared__ __align__(16) unsigned short As[8192];                          \
    __shared__ __align__(16) unsigned short Bs[8192];                          \
    const int tid  = threadIdx.x;                                              \
    const int wv   = tid >> 6, lane = tid & 63;                                \
    const int lm   = lane & 15, lq = lane >> 4;                                \
    const int m0   = blockIdx.y * 128;                                         \
    const int n0   = blockIdx.x * 128;                                         \
    const int wm   = wv >> 1, wn = wv & 1;                                     \
    f32x4 acc[4][4];                                                           \
    _Pragma("unroll")                                                          \
    for (int i = 0; i < 4; ++i)                                                \
        _Pragma("unroll")                                                      \
        for (int j = 0; j < 4; ++j) acc[i][j] = (f32x4){0.f,0.f,0.f,0.f};      \
    const int kbeg = blockIdx.z * kchunk, kend = kbeg + kchunk;                \
    for (int k0 = kbeg; k0 < kend; k0 += 64) {                                 \
        const int kb = k0 >> 11;                                               \
        const unsigned short* Ab = (kb == 1) ? Alo : Ahi;                      \
        const unsigned short* Bb = (kb == 2) ? Blo : Bhi;                      \
        const int kk = k0 & 2047;                                              \
        _Pragma("unroll")                                                      \
        for (int t = 0; t < 4; ++t) {                                          \
            int tt = wv*4 + t;                                                 \
            int rt = tt >> 1, kt = tt & 1;                                     \
            const unsigned short* ga =                                         \
                Ab + (size_t)(m0 + rt*16 + lm)*2048 + kk + kt*32 + lq*8;       \
            glds16(ga, &As[tt*512]);                                           \
            const unsigned short* gb =                                         \
                Bb + (size_t)(n0 + rt*16 + lm)*2048 + kk + kt*32 + lq*8;       \
            glds16(gb, &Bs[tt*512]);                                           \
        }                                                                      \
        __syncthreads();                                                       \
        _Pragma("unroll")                                                      \
        for (int ks = 0; ks < 2; ++ks) {                                       \
            short8 af[4], bf[4];                                               \
            _Pragma("unroll")                                                  \
            for (int i = 0; i < 4; ++i) {                                      \
                af[i] = *(const short8*)&As[((wm*4 + i)*2 + ks)*512 + lane*8]; \
                bf[i] = *(const short8*)&Bs[((wn*4 + i)*2 + ks)*512 + lane*8]; \
            }                                                                  \
            _Pragma("unroll")                                                  \
            for (int i = 0; i < 4; ++i)                                        \
                _Pragma("unroll")                                              \
                for (int j = 0; j < 4; ++j)                                    \
                    acc[i][j] = __builtin_amdgcn_mfma_f32_16x16x32_bf16(       \
                        af[i], bf[j], acc[i][j], 0, 0, 0);                     \
        }                                                                      \
        __syncthreads();                                                       \
    }

// Normal epilogue: C[row*ldc + col] (+ split-K partial offset).
__global__ __launch_bounds__(256) void gemm_mfma(
    const unsigned short* __restrict__ Ahi, const unsigned short* __restrict__ Alo,
    const unsigned short* __restrict__ Bhi, const unsigned short* __restrict__ Blo,
    float* __restrict__ Cbase, int ldc, int kchunk, size_t partstride)
{
    float* C = Cbase + (size_t)blockIdx.z * partstride;
    GEMM_BODY
    // C/D layout: col = lane&15, row = (lane>>4)*4 + reg
#pragma unroll
    for (int i = 0; i < 4; ++i) {
        int row = m0 + wm*64 + i*16 + lq*4;
#pragma unroll
        for (int j = 0; j < 4; ++j) {
            int col = n0 + wn*64 + j*16 + lm;
            float* cp = C + (size_t)row*ldc + col;
            cp[0*(size_t)ldc] = acc[i][j][0];
            cp[1*(size_t)ldc] = acc[i][j][1];
            cp[2*(size_t)ldc] = acc[i][j][2];
            cp[3*(size_t)ldc] = acc[i][j][3];
        }
    }
}

// Transposed epilogue: C[col*2048 + row] — reg dim (4 rows) is contiguous,
// one float4 store per (i,j) per lane. Used for ax = adj @ X^T.
__global__ __launch_bounds__(256) void gemm_mfma_T(
    const unsigned short* __restrict__ Ahi, const unsigned short* __restrict__ Alo,
    const unsigned short* __restrict__ Bhi, const unsigned short* __restrict__ Blo,
    float* __restrict__ Cbase, int kchunk, size_t partstride)
{
    float* C = Cbase + (size_t)blockIdx.z * partstride;
    GEMM_BODY
#pragma unroll
    for (int i = 0; i < 4; ++i) {
        int row = m0 + wm*64 + i*16 + lq*4;
#pragma unroll
        for (int j = 0; j < 4; ++j) {
            int col = n0 + wn*64 + j*16 + lm;
            float4 v = {acc[i][j][0], acc[i][j][1], acc[i][j][2], acc[i][j][3]};
            *(float4*)(C + (size_t)col*2048 + row) = v;
        }
    }
}

// ---------------------------------------------------------------------------
// Fused gate kernel: per block (node m, 32 batch rows):
//   gatesX = z_row @ Wc[64][384] + bc   (z row cols b*64+g, ld = ldz;
//                                        optional second partial zp1)
//   gatesH = h @ Whh[128][384] + bhh
//   r = sig, zg = sig, n = tanh(Xn + r*Hn), h' = (1-zg)n + zg h  (in place)
__device__ __forceinline__ float sigmoidf_(float x) {
    return 1.f / (1.f + __expf(-x));
}
__global__ __launch_bounds__(256) void gxgate(
    const float* __restrict__ zbase, int ldz, const float* __restrict__ zp1,
    const float* __restrict__ Wc,  const float* __restrict__ bc,
    const float* __restrict__ Whh, const float* __restrict__ bhh,
    float* __restrict__ h)
{
    const int m  = blockIdx.x;
    const int r0 = m * 32;
    __shared__ float zt[64][36];     // [g][b]
    __shared__ float a_t[32][36];    // [k][row]
    __shared__ float w_t[32][384];
    const int tid = threadIdx.x;
    const int cx = tid & 63;
    const int ry = tid >> 6;
    float bcv[6], bhv[6];
#pragma unroll
    for (int j = 0; j < 6; ++j) { bcv[j] = bc[cx + 64*j]; bhv[j] = bhh[cx + 64*j]; }

    {   // stage z row, transpose to [g][b]
        const float4* z0 = (const float4*)(zbase + (size_t)m*ldz);
        float4 u0 = z0[tid*2], u1 = z0[tid*2+1];
        if (zp1) {
            const float4* z1 = (const float4*)(zp1 + (size_t)m*ldz);
            float4 w0 = z1[tid*2], w1 = z1[tid*2+1];
            u0.x+=w0.x; u0.y+=w0.y; u0.z+=w0.z; u0.w+=w0.w;
            u1.x+=w1.x; u1.y+=w1.y; u1.z+=w1.z; u1.w+=w1.w;
        }
        int b = tid >> 3, g0 = (tid & 7) * 8;
        zt[g0+0][b] = u0.x; zt[g0+1][b] = u0.y;
        zt[g0+2][b] = u0.z; zt[g0+3][b] = u0.w;
        zt[g0+4][b] = u1.x; zt[g0+5][b] = u1.y;
        zt[g0+6][b] = u1.z; zt[g0+7][b] = u1.w;
    }
    float accx[8][6], acch[8][6];
#pragma unroll
    for (int i = 0; i < 8; ++i)
#pragma unroll
        for (int j = 0; j < 6; ++j) { accx[i][j] = 0.f; acch[i][j] = 0.f; }

    // phase 1: K=64 over Wc (x-path)
    for (int k0 = 0; k0 < 64; k0 += 32) {
#pragma unroll
        for (int l = 0; l < 12; ++l) {
            int idx = tid + 256*l;
            int wk = idx / 96, c4 = idx % 96;
            *(float4*)&w_t[wk][c4*4] =
                *(const float4*)(Wc + (size_t)(k0+wk)*384 + c4*4);
        }
        __syncthreads();
#pragma unroll 8
        for (int k = 0; k < 32; ++k) {
            float a[8];
            *(float4*)&a[0] = *(const float4*)&zt[k0+k][ry*8];
            *(float4*)&a[4] = *(const float4*)&zt[k0+k][ry*8+4];
            float b[6];
#pragma unroll
            for (int j = 0; j < 6; ++j) b[j] = w_t[k][cx + 64*j];
#pragma unroll
            for (int i = 0; i < 8; ++i)
#pragma unroll
                for (int j = 0; j < 6; ++j)
                    accx[i][j] = fmaf(a[i], b[j], accx[i][j]);
        }
        __syncthreads();
    }
    // phase 2: K=128 over Whh (h-path)
    for (int k0 = 0; k0 < HH; k0 += 32) {
        {
            int lr = tid >> 3, k4 = tid & 7;
            float4 v = *(const float4*)(h + (size_t)(r0+lr)*HH + k0 + k4*4);
            a_t[k4*4+0][lr] = v.x; a_t[k4*4+1][lr] = v.y;
            a_t[k4*4+2][lr] = v.z; a_t[k4*4+3][lr] = v.w;
#pragma unroll
            for (int l = 0; l < 12; ++l) {
                int idx = tid + 256*l;
                int wk = idx / 96, c4 = idx % 96;
                *(float4*)&w_t[wk][c4*4] =
                    *(const float4*)(Whh + (size_t)(k0+wk)*384 + c4*4);
            }
        }
        __syncthreads();
#pragma unroll 8
        for (int k = 0; k < 32; ++k) {
            float a[8];
            *(float4*)&a[0] = *(const float4*)&a_t[k][ry*8];
            *(float4*)&a[4] = *(const float4*)&a_t[k][ry*8+4];
            float b[6];
#pragma unroll
            for (int j = 0; j < 6; ++j) b[j] = w_t[k][cx + 64*j];
#pragma unroll
            for (int i = 0; i < 8; ++i)
#pragma unroll
                for (int j = 0; j < 6; ++j)
                    acch[i][j] = fmaf(a[i], b[j], acch[i][j]);
        }
        __syncthreads();
    }
    // epilogue
#pragma unroll
    for (int i = 0; i < 8; ++i) {
        int row = r0 + ry*8 + i;
        float* hp = h + (size_t)row*HH;
        float rx0 = accx[i][0]+bcv[0], rx1 = accx[i][1]+bcv[1];
        float zx0 = accx[i][2]+bcv[2], zx1 = accx[i][3]+bcv[3];
        float nx0 = accx[i][4]+bcv[4], nx1 = accx[i][5]+bcv[5];
        float rh0 = acch[i][0]+bhv[0], rh1 = acch[i][1]+bhv[1];
        float zh0 = acch[i][2]+bhv[2], zh1 = acch[i][3]+bhv[3];
        float nh0 = acch[i][4]+bhv[4], nh1 = acch[i][5]+bhv[5];
        float h0 = hp[cx], h1 = hp[cx+64];
        float r_0 = sigmoidf_(rx0 + rh0), r_1 = sigmoidf_(rx1 + rh1);
        float z_0 = sigmoidf_(zx0 + zh0), z_1 = sigmoidf_(zx1 + zh1);
        float n_0 = tanhf(nx0 + r_0*nh0), n_1 = tanhf(nx1 + r_1*nh1);
        hp[cx]    = (1.f - z_0)*n_0 + z_0*h0;
        hp[cx+64] = (1.f - z_1)*n_1 + z_1*h1;
    }
}

// ---------------------------------------------------------------------------
// xfc[b][n] = h[r] . W_fc + b_fc ; also writes d_out[b][p][n]
__global__ __launch_bounds__(256) void fck(
    const float* __restrict__ h,
    const float* __restrict__ Wfc, const float* __restrict__ bfc,
    float* __restrict__ out_p,
    float* __restrict__ xfc)
{
    int w = (blockIdx.x * 256 + threadIdx.x) >> 6;
    int lane = threadIdx.x & 63;
    const float2* hr = (const float2*)(h + (size_t)w*HH);
    const float2* wf = (const float2*)Wfc;
    float2 a = hr[lane], b2 = wf[lane];
    float s = a.x*b2.x + a.y*b2.y;
#pragma unroll
    for (int off = 32; off; off >>= 1) s += __shfl_xor(s, off);
    if (lane == 0) {
        s += bfc[0];
        int n = w >> 5, b = w & 31;
        out_p[(size_t)b*(PP*NN) + n] = s;
        xfc[(size_t)b*NN + n] = s;
    }
}

// ---------------------------------------------------------------------------
extern "C" void kernel_launch(void* const* d_in, const int* in_sizes, int n_in,
                              void* d_out, int out_size, void* d_ws, size_t ws_size,
                              hipStream_t stream)
{
    const float* x    = (const float*)d_in[0];
    const float* adj  = (const float*)d_in[1];
    const float* Wg1  = (const float*)d_in[2];
    const float* bg1  = (const float*)d_in[3];
    const float* Wg2  = (const float*)d_in[4];
    const float* bg2  = (const float*)d_in[5];
    const float* Wih  = (const float*)d_in[6];
    const float* Whh  = (const float*)d_in[7];
    const float* bih  = (const float*)d_in[8];
    const float* bhh  = (const float*)d_in[9];
    const float* Wfc  = (const float*)d_in[10];
    const float* bfc  = (const float*)d_in[11];

    float* ws = (float*)d_ws;
    float* Wc   = ws;                              // 64*384
    float* bc   = Wc + GG*384;                     // 1024 (384 used)
    float* hbuf = bc + 1024;                       // RR*HH (32 MB)
    float* xfc  = hbuf + (size_t)RR*HH;            // NB*NN
    float* AXe  = xfc + (size_t)NB*NN;             // 4 partials x 384 x 2048
    float* AXd  = AXe + (size_t)4*384*NN;          // 4 partials x 128 x 2048
    float* zg   = AXd + (size_t)4*128*NN;          // 3*2048*2048 (48 MB)
    unsigned short* Ahi  = (unsigned short*)(zg + (size_t)3*NN*NN);
    unsigned short* Alo  = Ahi  + (size_t)NN*NN;
    unsigned short* Xehi = Alo  + (size_t)NN*NN;   // 384 x 2048
    unsigned short* Xelo = Xehi + (size_t)384*NN;
    unsigned short* Xdhi = Xelo + (size_t)384*NN;  // 128 x 2048
    unsigned short* Xdlo = Xdhi + (size_t)128*NN;
    unsigned short* Hghi = Xdlo + (size_t)128*NN;  // 6144 x 2048 (24 MB)
    unsigned short* Hglo = Hghi + (size_t)6144*NN;
    // total ws use ~172 MiB

    hipMemsetAsync(hbuf, 0, (size_t)RR*HH*sizeof(float), stream);
    // zero decoder X pad rows 32..127 (persist across the launch)
    hipMemsetAsync(Xdhi + (size_t)32*NN, 0, (size_t)96*NN*sizeof(unsigned short), stream);
    hipMemsetAsync(Xdlo + (size_t)32*NN, 0, (size_t)96*NN*sizeof(unsigned short), stream);

    splitk<<<2048, 256, 0, stream>>>(adj, Ahi, Alo);
    wprep<<<98, 256, 0, stream>>>(Wg2, Wih, bih, bg2, Wc, bc);
    xsplit_enc<<<384, 256, 0, stream>>>(x, Xehi, Xelo);
    // encoder ax = adj @ Xe^T, all 12 steps at once (split-K 4, transposed C)
    gemm_mfma_T<<<dim3(3, 16, 4), 256, 0, stream>>>(
        Ahi, Alo, Xehi, Xelo, AXe, 6144/4, (size_t)384*NN);

    float* outp = (float*)d_out;

    // encoder: 4 groups of 3 steps; z-GEMM batched per group (N=6144 cols)
    for (int g = 0; g < 4; ++g) {
        h1T<<<dim3(NN, 3), 256, 0, stream>>>(
            AXe, g*96, (size_t)384*NN, Wg1, bg1, Hghi, Hglo);
        gemm_mfma<<<dim3(48, 16, 1), 256, 0, stream>>>(
            Ahi, Alo, Hghi, Hglo, zg, 6144, 6144, 0);
        for (int ty = 0; ty < 3; ++ty)
            gxgate<<<NN, 256, 0, stream>>>(
                zg + ty*NN, 6144, nullptr, Wc, bc, Whh, bhh, hbuf);
    }
    // decoder
    for (int p = 0; p < PP; ++p) {
        fck<<<RR/4, 256, 0, stream>>>(hbuf, Wfc, bfc, outp + (size_t)p*NN, xfc);
        if (p < PP-1) {
            xsplit_dec<<<32, 256, 0, stream>>>(xfc, Xdhi, Xdlo);
            gemm_mfma_T<<<dim3(1, 16, 4), 256, 0, stream>>>(
                Ahi, Alo, Xdhi, Xdlo, AXd, 6144/4, (size_t)128*NN);
            h1T<<<dim3(NN, 1), 256, 0, stream>>>(
                AXd, 0, (size_t)128*NN, Wg1, bg1, Hghi, Hglo);
            gemm_mfma<<<dim3(16, 16, 2), 256, 0, stream>>>(
                Ahi, Alo, Hghi, Hglo, zg, 2048, 3072, (size_t)NN*NN);
            gxgate<<<NN, 256, 0, stream>>>(
                zg, 2048, zg + (size_t)NN*NN, Wc, bc, Whh, bhh, hbuf);
        }
    }
}

// Round 5
// 3847.733 us; speedup vs baseline: 2.6325x; 1.0266x over previous
//
#include <hip/hip_runtime.h>
#include <math.h>

// Problem constants: B=32, S=12, N=2048, F=1, H=128, G=64, O=1, P=3
#define NB 32
#define SS 12
#define NN 2048
#define HH 128
#define GG 64
#define PP 3
#define RR (NN*NB)   // 65536 rows, node-major r = n*32 + b

typedef __attribute__((ext_vector_type(8))) short short8;   // 8 bf16 (4 VGPRs)
typedef __attribute__((ext_vector_type(4))) float f32x4;

__device__ __forceinline__ unsigned short f2bf(float f) {   // RNE fp32->bf16
    unsigned b = __float_as_uint(f);
    return (unsigned short)((b + 0x7FFFu + ((b >> 16) & 1u)) >> 16);
}
__device__ __forceinline__ float bf2f(unsigned short u) {
    return __uint_as_float(((unsigned)u) << 16);
}
__device__ __forceinline__ void glds16(const void* g, const void* l) {
    __builtin_amdgcn_global_load_lds(
        (const __attribute__((address_space(1))) void*)g,
        (__attribute__((address_space(3))) void*)l, 16, 0, 0);
}

// ---------------------------------------------------------------------------
// split fp32 -> bf16 hi + bf16 lo  (lo = bf16(x - fp32(hi)))
__global__ __launch_bounds__(256) void splitk(
    const float* __restrict__ src,
    unsigned short* __restrict__ hi, unsigned short* __restrict__ lo)
{
    size_t i0 = ((size_t)blockIdx.x * 256 + threadIdx.x) * 8;
    float4 v0 = *(const float4*)(src + i0);
    float4 v1 = *(const float4*)(src + i0 + 4);
    float f[8] = {v0.x,v0.y,v0.z,v0.w,v1.x,v1.y,v1.z,v1.w};
    union { unsigned short u[8]; uint4 q; } H, L;
#pragma unroll
    for (int k = 0; k < 8; ++k) {
        unsigned short h = f2bf(f[k]);
        H.u[k] = h;
        L.u[k] = f2bf(f[k] - bf2f(h));
    }
    *(uint4*)(hi + i0) = H.q;
    *(uint4*)(lo + i0) = L.q;
}

// ---------------------------------------------------------------------------
// Encoder x -> split rows [(t*32+b)][n] from x[b][t][n]. 384 blocks.
__global__ __launch_bounds__(256) void xsplit_enc(
    const float* __restrict__ x,
    unsigned short* __restrict__ hi, unsigned short* __restrict__ lo)
{
    const int row = blockIdx.x;            // t*32 + b
    const int t = row >> 5, b = row & 31;
    const size_t n0 = (size_t)threadIdx.x * 8;
    const float* src = x + ((size_t)b*SS + t)*NN;
    float4 v0 = *(const float4*)(src + n0);
    float4 v1 = *(const float4*)(src + n0 + 4);
    float f[8] = {v0.x,v0.y,v0.z,v0.w,v1.x,v1.y,v1.z,v1.w};
    union { unsigned short u[8]; uint4 q; } H, L;
#pragma unroll
    for (int k = 0; k < 8; ++k) {
        unsigned short h = f2bf(f[k]);
        H.u[k] = h;
        L.u[k] = f2bf(f[k] - bf2f(h));
    }
    *(uint4*)(hi + (size_t)row*NN + n0) = H.q;
    *(uint4*)(lo + (size_t)row*NN + n0) = L.q;
}

// Decoder xfc[b][n] -> split rows [b][n] (rows 32..127 pre-zeroed). 32 blocks.
__global__ __launch_bounds__(256) void xsplit_dec(
    const float* __restrict__ xfc,
    unsigned short* __restrict__ hi, unsigned short* __restrict__ lo)
{
    const int b = blockIdx.x;
    const size_t n0 = (size_t)threadIdx.x * 8;
    const float* src = xfc + (size_t)b*NN;
    float4 v0 = *(const float4*)(src + n0);
    float4 v1 = *(const float4*)(src + n0 + 4);
    float f[8] = {v0.x,v0.y,v0.z,v0.w,v1.x,v1.y,v1.z,v1.w};
    union { unsigned short u[8]; uint4 q; } H, L;
#pragma unroll
    for (int k = 0; k < 8; ++k) {
        unsigned short h = f2bf(f[k]);
        H.u[k] = h;
        L.u[k] = f2bf(f[k] - bf2f(h));
    }
    *(uint4*)(hi + (size_t)b*NN + n0) = H.q;
    *(uint4*)(lo + (size_t)b*NN + n0) = L.q;
}

// ---------------------------------------------------------------------------
// Precompute Wc[64][384] = Wg2 @ Wih and bc[384] = bg2 @ Wih + bih.
__global__ __launch_bounds__(256) void wprep(
    const float* __restrict__ Wg2, const float* __restrict__ Wih,
    const float* __restrict__ bih, const float* __restrict__ bg2,
    float* __restrict__ Wc, float* __restrict__ bc)
{
    int idx = blockIdx.x * 256 + threadIdx.x;
    if (idx < GG*384) {
        int g = idx / 384, o = idx % 384;
        float s = 0.f;
        for (int k = 0; k < HH; ++k)
            s = fmaf(Wg2[g*HH + k], Wih[k*384 + o], s);
        Wc[idx] = s;
    } else if (idx < GG*384 + 384) {
        int o = idx - GG*384;
        float s = bih[o];
        for (int k = 0; k < HH; ++k)
            s = fmaf(bg2[k], Wih[k*384 + o], s);
        bc[o] = s;
    }
}

// ---------------------------------------------------------------------------
// h1 from ax partials: H[(ty*2048 + c)][n] = relu(ax[.]*W1[g]+b1[g]) split,
// c = b*64+g; ax row in AX-part buffer = col_base + ty*32 + b, summed over
// 4 split-K partials (part_stride apart). grid (2048, nt).
__global__ __launch_bounds__(256) void h1T(
    const float* __restrict__ axpart, int col_base, size_t part_stride,
    const float* __restrict__ Wg1, const float* __restrict__ bg1,
    unsigned short* __restrict__ Hhi, unsigned short* __restrict__ Hlo)
{
    const int c = blockIdx.x;
    const int ty = blockIdx.y;
    const int b = c >> 6, g = c & 63;
    const float w1 = Wg1[g], b1 = bg1[g];
    const size_t n0 = (size_t)threadIdx.x * 8;
    const size_t rowoff = (size_t)(col_base + ty*32 + b) * NN + n0;
    float f[8] = {0,0,0,0,0,0,0,0};
#pragma unroll
    for (int p = 0; p < 4; ++p) {
        const float4* q = (const float4*)(axpart + p*part_stride + rowoff);
        float4 v0 = q[0], v1 = q[1];
        f[0]+=v0.x; f[1]+=v0.y; f[2]+=v0.z; f[3]+=v0.w;
        f[4]+=v1.x; f[5]+=v1.y; f[6]+=v1.z; f[7]+=v1.w;
    }
    union { unsigned short u[8]; uint4 q; } H, L;
#pragma unroll
    for (int k = 0; k < 8; ++k) {
        float v = fmaxf(fmaf(f[k], w1, b1), 0.f);
        unsigned short h = f2bf(v);
        H.u[k] = h;
        L.u[k] = f2bf(v - bf2f(h));
    }
    size_t base = ((size_t)ty*2048 + c) * NN + n0;
    *(uint4*)(Hhi + base) = H.q;
    *(uint4*)(Hlo + base) = L.q;
}

// ---------------------------------------------------------------------------
// Split-bf16 MFMA GEMM core (Ahi@Bhi + Alo@Bhi + Ahi@Blo over K=3*2048).
// A rows = m (2048, k-stride 2048); B rows = output cols (k-stride 2048).
// 128x128 tile, BK=64, global_load_lds 16B, 16x16x32 MFMA.
// Block-id swizzle: m-tile-fast (16 consecutive blocks share one B col-tile)
// for L2 reuse of the streamed B operand. All call sites have gridDim.y==16.
#define GEMM_BODY                                                              \
    __shared__ __align__(16) unsigned short As[8192];                          \
    __shared__ __align__(16) unsigned short Bs[8192];                          \
    const int tid  = threadIdx.x;                                              \
    const int wv   = tid >> 6, lane = tid & 63;                                \
    const int lm   = lane & 15, lq = lane >> 4;                                \
    const int id_  = blockIdx.y * gridDim.x + blockIdx.x;                      \
    const int m0   = (id_ & 15) * 128;                                         \
    const int n0   = (id_ >> 4) * 128;                                         \
    const int wm   = wv >> 1, wn = wv & 1;                                     \
    f32x4 acc[4][4];                                                           \
    _Pragma("unroll")                                                          \
    for (int i = 0; i < 4; ++i)                                                \
        _Pragma("unroll")                                                      \
        for (int j = 0; j < 4; ++j) acc[i][j] = (f32x4){0.f,0.f,0.f,0.f};      \
    const int kbeg = blockIdx.z * kchunk, kend = kbeg + kchunk;                \
    for (int k0 = kbeg; k0 < kend; k0 += 64) {                                 \
        const int kb = k0 >> 11;                                               \
        const unsigned short* Ab = (kb == 1) ? Alo : Ahi;                      \
        const unsigned short* Bb = (kb == 2) ? Blo : Bhi;                      \
        const int kk = k0 & 2047;                                              \
        _Pragma("unroll")                                                      \
        for (int t = 0; t < 4; ++t) {                                          \
            int tt = wv*4 + t;                                                 \
            int rt = tt >> 1, kt = tt & 1;                                     \
            const unsigned short* ga =                                         \
                Ab + (size_t)(m0 + rt*16 + lm)*2048 + kk + kt*32 + lq*8;       \
            glds16(ga, &As[tt*512]);                                           \
            const unsigned short* gb =                                         \
                Bb + (size_t)(n0 + rt*16 + lm)*2048 + kk + kt*32 + lq*8;       \
            glds16(gb, &Bs[tt*512]);                                           \
        }                                                                      \
        __syncthreads();                                                       \
        _Pragma("unroll")                                                      \
        for (int ks = 0; ks < 2; ++ks) {                                       \
            short8 af[4], bf[4];                                               \
            _Pragma("unroll")                                                  \
            for (int i = 0; i < 4; ++i) {                                      \
                af[i] = *(const short8*)&As[((wm*4 + i)*2 + ks)*512 + lane*8]; \
                bf[i] = *(const short8*)&Bs[((wn*4 + i)*2 + ks)*512 + lane*8]; \
            }                                                                  \
            _Pragma("unroll")                                                  \
            for (int i = 0; i < 4; ++i)                                        \
                _Pragma("unroll")                                              \
                for (int j = 0; j < 4; ++j)                                    \
                    acc[i][j] = __builtin_amdgcn_mfma_f32_16x16x32_bf16(       \
                        af[i], bf[j], acc[i][j], 0, 0, 0);                     \
        }                                                                      \
        __syncthreads();                                                       \
    }

// Normal epilogue: C[row*ldc + col] (+ split-K partial offset).
__global__ __launch_bounds__(256) void gemm_mfma(
    const unsigned short* __restrict__ Ahi, const unsigned short* __restrict__ Alo,
    const unsigned short* __restrict__ Bhi, const unsigned short* __restrict__ Blo,
    float* __restrict__ Cbase, int ldc, int kchunk, size_t partstride)
{
    float* C = Cbase + (size_t)blockIdx.z * partstride;
    GEMM_BODY
    // C/D layout: col = lane&15, row = (lane>>4)*4 + reg
#pragma unroll
    for (int i = 0; i < 4; ++i) {
        int row = m0 + wm*64 + i*16 + lq*4;
#pragma unroll
        for (int j = 0; j < 4; ++j) {
            int col = n0 + wn*64 + j*16 + lm;
            float* cp = C + (size_t)row*ldc + col;
            cp[0*(size_t)ldc] = acc[i][j][0];
            cp[1*(size_t)ldc] = acc[i][j][1];
            cp[2*(size_t)ldc] = acc[i][j][2];
            cp[3*(size_t)ldc] = acc[i][j][3];
        }
    }
}

// Transposed epilogue: C[col*2048 + row] — reg dim (4 rows) is contiguous,
// one float4 store per (i,j) per lane. Used for ax = adj @ X^T.
__global__ __launch_bounds__(256) void gemm_mfma_T(
    const unsigned short* __restrict__ Ahi, const unsigned short* __restrict__ Alo,
    const unsigned short* __restrict__ Bhi, const unsigned short* __restrict__ Blo,
    float* __restrict__ Cbase, int kchunk, size_t partstride)
{
    float* C = Cbase + (size_t)blockIdx.z * partstride;
    GEMM_BODY
#pragma unroll
    for (int i = 0; i < 4; ++i) {
        int row = m0 + wm*64 + i*16 + lq*4;
#pragma unroll
        for (int j = 0; j < 4; ++j) {
            int col = n0 + wn*64 + j*16 + lm;
            float4 v = {acc[i][j][0], acc[i][j][1], acc[i][j][2], acc[i][j][3]};
            *(float4*)(C + (size_t)col*2048 + row) = v;
        }
    }
}

// ---------------------------------------------------------------------------
// Fused gate kernel (restructured for occupancy): per block (node m, 32 rows):
//   gatesX = z_row @ Wc[64][384] + bc  (z cols b*64+g, ld = ldz; opt. zp1)
//   gatesH = h @ Whh[128][384] + bhh
//   r = sig, zg = sig, n = tanh(Xn + r*Hn), h' = (1-zg)n + zg h  (in place)
// No weight LDS staging: Wc/Whh read directly (coalesced, L2-resident,
// identical across blocks). zt + full h-tile staged once; ONE barrier.
// r/z-gate H-contributions accumulate into accx (only n needs separation),
// so acc = 48+16 = 64 regs -> 4 blocks/CU (LDS 27.6 KB, VGPR<=128).
__device__ __forceinline__ float sigmoidf_(float x) {
    return 1.f / (1.f + __expf(-x));
}
__global__ __launch_bounds__(256, 4) void gxgate(
    const float* __restrict__ zbase, int ldz, const float* __restrict__ zp1,
    const float* __restrict__ Wc,  const float* __restrict__ bc,
    const float* __restrict__ Whh, const float* __restrict__ bhh,
    float* __restrict__ h)
{
    const int m  = blockIdx.x;
    const int r0 = m * 32;
    __shared__ float zt[64][36];      // [g][b]
    __shared__ float a_t[128][36];    // [k][row] full h-tile
    const int tid = threadIdx.x;
    const int cx = tid & 63;
    const int ry = tid >> 6;
    float bcv[6], bhv[6];
#pragma unroll
    for (int j = 0; j < 6; ++j) { bcv[j] = bc[cx + 64*j]; bhv[j] = bhh[cx + 64*j]; }

    {   // stage z row (optional split-K partial sum), transpose to [g][b]
        const float4* z0 = (const float4*)(zbase + (size_t)m*ldz);
        float4 u0 = z0[tid*2], u1 = z0[tid*2+1];
        if (zp1) {
            const float4* z1 = (const float4*)(zp1 + (size_t)m*ldz);
            float4 w0 = z1[tid*2], w1 = z1[tid*2+1];
            u0.x+=w0.x; u0.y+=w0.y; u0.z+=w0.z; u0.w+=w0.w;
            u1.x+=w1.x; u1.y+=w1.y; u1.z+=w1.z; u1.w+=w1.w;
        }
        int b = tid >> 3, g0 = (tid & 7) * 8;
        zt[g0+0][b] = u0.x; zt[g0+1][b] = u0.y;
        zt[g0+2][b] = u0.z; zt[g0+3][b] = u0.w;
        zt[g0+4][b] = u1.x; zt[g0+5][b] = u1.y;
        zt[g0+6][b] = u1.z; zt[g0+7][b] = u1.w;
    }
    {   // stage full h tile [128k][32r]: 1024 float4 = 256 thr x 4
#pragma unroll
        for (int p = 0; p < 4; ++p) {
            int idx = tid + 256*p;
            int lr = idx & 31, kq = idx >> 5;     // row, k-quad
            float4 v = *(const float4*)(h + (size_t)(r0+lr)*HH + kq*4);
            a_t[kq*4+0][lr] = v.x; a_t[kq*4+1][lr] = v.y;
            a_t[kq*4+2][lr] = v.z; a_t[kq*4+3][lr] = v.w;
        }
    }
    __syncthreads();

    float accx[8][6], acchn[8][2];
#pragma unroll
    for (int i = 0; i < 8; ++i) {
#pragma unroll
        for (int j = 0; j < 6; ++j) accx[i][j] = 0.f;
        acchn[i][0] = 0.f; acchn[i][1] = 0.f;
    }

    // phase 1: K=64 over Wc (x-path), a from zt (wave-uniform broadcast)
#pragma unroll 8
    for (int k = 0; k < 64; ++k) {
        float a[8];
        *(float4*)&a[0] = *(const float4*)&zt[k][ry*8];
        *(float4*)&a[4] = *(const float4*)&zt[k][ry*8+4];
        float b[6];
#pragma unroll
        for (int j = 0; j < 6; ++j) b[j] = Wc[k*384 + cx + 64*j];
#pragma unroll
        for (int i = 0; i < 8; ++i)
#pragma unroll
            for (int j = 0; j < 6; ++j)
                accx[i][j] = fmaf(a[i], b[j], accx[i][j]);
    }
    // phase 2: K=128 over Whh (h-path); r/z into accx, n separate
#pragma unroll 8
    for (int k = 0; k < HH; ++k) {
        float a[8];
        *(float4*)&a[0] = *(const float4*)&a_t[k][ry*8];
        *(float4*)&a[4] = *(const float4*)&a_t[k][ry*8+4];
        float b[6];
#pragma unroll
        for (int j = 0; j < 6; ++j) b[j] = Whh[k*384 + cx + 64*j];
#pragma unroll
        for (int i = 0; i < 8; ++i) {
#pragma unroll
            for (int j = 0; j < 4; ++j)
                accx[i][j] = fmaf(a[i], b[j], accx[i][j]);
            acchn[i][0] = fmaf(a[i], b[4], acchn[i][0]);
            acchn[i][1] = fmaf(a[i], b[5], acchn[i][1]);
        }
    }
    // epilogue: cols {cx, cx+64} of r/z/n for rows ry*8+i
#pragma unroll
    for (int i = 0; i < 8; ++i) {
        int row = r0 + ry*8 + i;
        float* hp = h + (size_t)row*HH;
        float rp0 = accx[i][0]+bcv[0]+bhv[0], rp1 = accx[i][1]+bcv[1]+bhv[1];
        float zp_0 = accx[i][2]+bcv[2]+bhv[2], zp_1 = accx[i][3]+bcv[3]+bhv[3];
        float nx0 = accx[i][4]+bcv[4],        nx1 = accx[i][5]+bcv[5];
        float nh0 = acchn[i][0]+bhv[4],       nh1 = acchn[i][1]+bhv[5];
        float h0 = hp[cx], h1 = hp[cx+64];
        float r_0 = sigmoidf_(rp0), r_1 = sigmoidf_(rp1);
        float z_0 = sigmoidf_(zp_0), z_1 = sigmoidf_(zp_1);
        float n_0 = tanhf(nx0 + r_0*nh0), n_1 = tanhf(nx1 + r_1*nh1);
        hp[cx]    = (1.f - z_0)*n_0 + z_0*h0;
        hp[cx+64] = (1.f - z_1)*n_1 + z_1*h1;
    }
}

// ---------------------------------------------------------------------------
// xfc[b][n] = h[r] . W_fc + b_fc ; also writes d_out[b][p][n]
__global__ __launch_bounds__(256) void fck(
    const float* __restrict__ h,
    const float* __restrict__ Wfc, const float* __restrict__ bfc,
    float* __restrict__ out_p,
    float* __restrict__ xfc)
{
    int w = (blockIdx.x * 256 + threadIdx.x) >> 6;
    int lane = threadIdx.x & 63;
    const float2* hr = (const float2*)(h + (size_t)w*HH);
    const float2* wf = (const float2*)Wfc;
    float2 a = hr[lane], b2 = wf[lane];
    float s = a.x*b2.x + a.y*b2.y;
#pragma unroll
    for (int off = 32; off; off >>= 1) s += __shfl_xor(s, off);
    if (lane == 0) {
        s += bfc[0];
        int n = w >> 5, b = w & 31;
        out_p[(size_t)b*(PP*NN) + n] = s;
        xfc[(size_t)b*NN + n] = s;
    }
}

// ---------------------------------------------------------------------------
extern "C" void kernel_launch(void* const* d_in, const int* in_sizes, int n_in,
                              void* d_out, int out_size, void* d_ws, size_t ws_size,
                              hipStream_t stream)
{
    const float* x    = (const float*)d_in[0];
    const float* adj  = (const float*)d_in[1];
    const float* Wg1  = (const float*)d_in[2];
    const float* bg1  = (const float*)d_in[3];
    const float* Wg2  = (const float*)d_in[4];
    const float* bg2  = (const float*)d_in[5];
    const float* Wih  = (const float*)d_in[6];
    const float* Whh  = (const float*)d_in[7];
    const float* bih  = (const float*)d_in[8];
    const float* bhh  = (const float*)d_in[9];
    const float* Wfc  = (const float*)d_in[10];
    const float* bfc  = (const float*)d_in[11];

    float* ws = (float*)d_ws;
    float* Wc   = ws;                              // 64*384
    float* bc   = Wc + GG*384;                     // 1024 (384 used)
    float* hbuf = bc + 1024;                       // RR*HH (32 MB)
    float* xfc  = hbuf + (size_t)RR*HH;            // NB*NN
    float* AXe  = xfc + (size_t)NB*NN;             // 4 partials x 384 x 2048
    float* AXd  = AXe + (size_t)4*384*NN;          // 4 partials x 128 x 2048
    float* zg   = AXd + (size_t)4*128*NN;          // 3*2048*2048 (48 MB)
    unsigned short* Ahi  = (unsigned short*)(zg + (size_t)3*NN*NN);
    unsigned short* Alo  = Ahi  + (size_t)NN*NN;
    unsigned short* Xehi = Alo  + (size_t)NN*NN;   // 384 x 2048
    unsigned short* Xelo = Xehi + (size_t)384*NN;
    unsigned short* Xdhi = Xelo + (size_t)384*NN;  // 128 x 2048
    unsigned short* Xdlo = Xdhi + (size_t)128*NN;
    unsigned short* Hghi = Xdlo + (size_t)128*NN;  // 6144 x 2048 (24 MB)
    unsigned short* Hglo = Hghi + (size_t)6144*NN;
    // total ws use ~172 MiB

    hipMemsetAsync(hbuf, 0, (size_t)RR*HH*sizeof(float), stream);
    // zero decoder X pad rows 32..127 (persist across the launch)
    hipMemsetAsync(Xdhi + (size_t)32*NN, 0, (size_t)96*NN*sizeof(unsigned short), stream);
    hipMemsetAsync(Xdlo + (size_t)32*NN, 0, (size_t)96*NN*sizeof(unsigned short), stream);

    splitk<<<2048, 256, 0, stream>>>(adj, Ahi, Alo);
    wprep<<<98, 256, 0, stream>>>(Wg2, Wih, bih, bg2, Wc, bc);
    xsplit_enc<<<384, 256, 0, stream>>>(x, Xehi, Xelo);
    // encoder ax = adj @ Xe^T, all 12 steps at once (split-K 4, transposed C)
    gemm_mfma_T<<<dim3(3, 16, 4), 256, 0, stream>>>(
        Ahi, Alo, Xehi, Xelo, AXe, 6144/4, (size_t)384*NN);

    float* outp = (float*)d_out;

    // encoder: 4 groups of 3 steps; z-GEMM batched per group (N=6144 cols)
    for (int g = 0; g < 4; ++g) {
        h1T<<<dim3(NN, 3), 256, 0, stream>>>(
            AXe, g*96, (size_t)384*NN, Wg1, bg1, Hghi, Hglo);
        gemm_mfma<<<dim3(48, 16, 1), 256, 0, stream>>>(
            Ahi, Alo, Hghi, Hglo, zg, 6144, 6144, 0);
        for (int ty = 0; ty < 3; ++ty)
            gxgate<<<NN, 256, 0, stream>>>(
                zg + ty*NN, 6144, nullptr, Wc, bc, Whh, bhh, hbuf);
    }
    // decoder
    for (int p = 0; p < PP; ++p) {
        fck<<<RR/4, 256, 0, stream>>>(hbuf, Wfc, bfc, outp + (size_t)p*NN, xfc);
        if (p < PP-1) {
            xsplit_dec<<<32, 256, 0, stream>>>(xfc, Xdhi, Xdlo);
            gemm_mfma_T<<<dim3(1, 16, 4), 256, 0, stream>>>(
                Ahi, Alo, Xdhi, Xdlo, AXd, 6144/4, (size_t)128*NN);
            h1T<<<dim3(NN, 1), 256, 0, stream>>>(
                AXd, 0, (size_t)128*NN, Wg1, bg1, Hghi, Hglo);
            gemm_mfma<<<dim3(16, 16, 2), 256, 0, stream>>>(
                Ahi, Alo, Hghi, Hglo, zg, 2048, 3072, (size_t)NN*NN);
            gxgate<<<NN, 256, 0, stream>>>(
                zg, 2048, zg + (size_t)NN*NN, Wc, bc, Whh, bhh, hbuf);
        }
    }
}

// Round 6
// 3211.695 us; speedup vs baseline: 3.1539x; 1.1980x over previous
//
#include <hip/hip_runtime.h>
#include <math.h>

// Problem constants: B=32, S=12, N=2048, F=1, H=128, G=64, O=1, P=3
#define NB 32
#define SS 12
#define NN 2048
#define HH 128
#define GG 64
#define PP 3
#define RR (NN*NB)   // 65536 rows, node-major r = n*32 + b

typedef __attribute__((ext_vector_type(8))) short short8;   // 8 bf16 (4 VGPRs)
typedef __attribute__((ext_vector_type(4))) float f32x4;

__device__ __forceinline__ unsigned short f2bf(float f) {   // RNE fp32->bf16
    unsigned b = __float_as_uint(f);
    return (unsigned short)((b + 0x7FFFu + ((b >> 16) & 1u)) >> 16);
}
__device__ __forceinline__ float bf2f(unsigned short u) {
    return __uint_as_float(((unsigned)u) << 16);
}
__device__ __forceinline__ void glds16(const void* g, const void* l) {
    __builtin_amdgcn_global_load_lds(
        (const __attribute__((address_space(1))) void*)g,
        (__attribute__((address_space(3))) void*)l, 16, 0, 0);
}

// ---------------------------------------------------------------------------
// split fp32 -> bf16 hi + bf16 lo  (lo = bf16(x - fp32(hi)))
__global__ __launch_bounds__(256) void splitk(
    const float* __restrict__ src,
    unsigned short* __restrict__ hi, unsigned short* __restrict__ lo)
{
    size_t i0 = ((size_t)blockIdx.x * 256 + threadIdx.x) * 8;
    float4 v0 = *(const float4*)(src + i0);
    float4 v1 = *(const float4*)(src + i0 + 4);
    float f[8] = {v0.x,v0.y,v0.z,v0.w,v1.x,v1.y,v1.z,v1.w};
    union { unsigned short u[8]; uint4 q; } H, L;
#pragma unroll
    for (int k = 0; k < 8; ++k) {
        unsigned short h = f2bf(f[k]);
        H.u[k] = h;
        L.u[k] = f2bf(f[k] - bf2f(h));
    }
    *(uint4*)(hi + i0) = H.q;
    *(uint4*)(lo + i0) = L.q;
}

// ---------------------------------------------------------------------------
// Encoder x -> split rows [(t*32+b)][n] from x[b][t][n]. 384 blocks.
__global__ __launch_bounds__(256) void xsplit_enc(
    const float* __restrict__ x,
    unsigned short* __restrict__ hi, unsigned short* __restrict__ lo)
{
    const int row = blockIdx.x;            // t*32 + b
    const int t = row >> 5, b = row & 31;
    const size_t n0 = (size_t)threadIdx.x * 8;
    const float* src = x + ((size_t)b*SS + t)*NN;
    float4 v0 = *(const float4*)(src + n0);
    float4 v1 = *(const float4*)(src + n0 + 4);
    float f[8] = {v0.x,v0.y,v0.z,v0.w,v1.x,v1.y,v1.z,v1.w};
    union { unsigned short u[8]; uint4 q; } H, L;
#pragma unroll
    for (int k = 0; k < 8; ++k) {
        unsigned short h = f2bf(f[k]);
        H.u[k] = h;
        L.u[k] = f2bf(f[k] - bf2f(h));
    }
    *(uint4*)(hi + (size_t)row*NN + n0) = H.q;
    *(uint4*)(lo + (size_t)row*NN + n0) = L.q;
}

// Decoder xfc[b][n] -> split rows [b][n] (rows 32..127 pre-zeroed). 32 blocks.
__global__ __launch_bounds__(256) void xsplit_dec(
    const float* __restrict__ xfc,
    unsigned short* __restrict__ hi, unsigned short* __restrict__ lo)
{
    const int b = blockIdx.x;
    const size_t n0 = (size_t)threadIdx.x * 8;
    const float* src = xfc + (size_t)b*NN;
    float4 v0 = *(const float4*)(src + n0);
    float4 v1 = *(const float4*)(src + n0 + 4);
    float f[8] = {v0.x,v0.y,v0.z,v0.w,v1.x,v1.y,v1.z,v1.w};
    union { unsigned short u[8]; uint4 q; } H, L;
#pragma unroll
    for (int k = 0; k < 8; ++k) {
        unsigned short h = f2bf(f[k]);
        H.u[k] = h;
        L.u[k] = f2bf(f[k] - bf2f(h));
    }
    *(uint4*)(hi + (size_t)b*NN + n0) = H.q;
    *(uint4*)(lo + (size_t)b*NN + n0) = L.q;
}

// ---------------------------------------------------------------------------
// Precompute Wc[64][384] = Wg2 @ Wih and bc[384] = bg2 @ Wih + bih.
__global__ __launch_bounds__(256) void wprep(
    const float* __restrict__ Wg2, const float* __restrict__ Wih,
    const float* __restrict__ bih, const float* __restrict__ bg2,
    float* __restrict__ Wc, float* __restrict__ bc)
{
    int idx = blockIdx.x * 256 + threadIdx.x;
    if (idx < GG*384) {
        int g = idx / 384, o = idx % 384;
        float s = 0.f;
        for (int k = 0; k < HH; ++k)
            s = fmaf(Wg2[g*HH + k], Wih[k*384 + o], s);
        Wc[idx] = s;
    } else if (idx < GG*384 + 384) {
        int o = idx - GG*384;
        float s = bih[o];
        for (int k = 0; k < HH; ++k)
            s = fmaf(bg2[k], Wih[k*384 + o], s);
        bc[o] = s;
    }
}

// ---------------------------------------------------------------------------
// h1 from ax partials: H[(ty*2048 + c)][n] = relu(ax[.]*W1[g]+b1[g]) split,
// c = b*64+g; ax row in AX-part buffer = col_base + ty*32 + b, summed over
// 4 split-K partials (part_stride apart). grid (2048, nt).
__global__ __launch_bounds__(256) void h1T(
    const float* __restrict__ axpart, int col_base, size_t part_stride,
    const float* __restrict__ Wg1, const float* __restrict__ bg1,
    unsigned short* __restrict__ Hhi, unsigned short* __restrict__ Hlo)
{
    const int c = blockIdx.x;
    const int ty = blockIdx.y;
    const int b = c >> 6, g = c & 63;
    const float w1 = Wg1[g], b1 = bg1[g];
    const size_t n0 = (size_t)threadIdx.x * 8;
    const size_t rowoff = (size_t)(col_base + ty*32 + b) * NN + n0;
    float f[8] = {0,0,0,0,0,0,0,0};
#pragma unroll
    for (int p = 0; p < 4; ++p) {
        const float4* q = (const float4*)(axpart + p*part_stride + rowoff);
        float4 v0 = q[0], v1 = q[1];
        f[0]+=v0.x; f[1]+=v0.y; f[2]+=v0.z; f[3]+=v0.w;
        f[4]+=v1.x; f[5]+=v1.y; f[6]+=v1.z; f[7]+=v1.w;
    }
    union { unsigned short u[8]; uint4 q; } H, L;
#pragma unroll
    for (int k = 0; k < 8; ++k) {
        float v = fmaxf(fmaf(f[k], w1, b1), 0.f);
        unsigned short h = f2bf(v);
        H.u[k] = h;
        L.u[k] = f2bf(v - bf2f(h));
    }
    size_t base = ((size_t)ty*2048 + c) * NN + n0;
    *(uint4*)(Hhi + base) = H.q;
    *(uint4*)(Hlo + base) = L.q;
}

// ---------------------------------------------------------------------------
// Split-bf16 MFMA GEMM, FUSED 3-term K-loop: per 32-K chunk stage all four
// tiles (Ahi,Alo,Bhi,Blo; 32 KB, one barrier pair) and run all 48 MFMAs
// (Ahi*Bhi + Ahi*Blo + Alo*Bhi), reusing ah/bh fragments across terms.
// 1.5x less staging + 3x fewer barriers than term-sequential K=3*2048.
// kchunk is the LOGICAL K chunk per blockIdx.z (split-K).
// Each wave stages one matrix (wv: 0=Ahi 1=Alo 2=Bhi 3=Blo), 8 tiles of
// 16 rows x 32 k each.
#define GEMM_BODY                                                              \
    __shared__ __align__(16) unsigned short As[8192];  /* [0]=hi [4096]=lo */  \
    __shared__ __align__(16) unsigned short Bs[8192];                          \
    const int tid  = threadIdx.x;                                              \
    const int wv   = tid >> 6, lane = tid & 63;                                \
    const int lm   = lane & 15, lq = lane >> 4;                                \
    const int m0   = blockIdx.y * 128;                                         \
    const int n0   = blockIdx.x * 128;                                         \
    const int wm   = wv >> 1, wn = wv & 1;                                     \
    const unsigned short* smat = (wv==0) ? Ahi : (wv==1) ? Alo                 \
                               : (wv==2) ? Bhi : Blo;                          \
    const int srow = (wv < 2) ? m0 : n0;                                       \
    unsigned short* sdst = ((wv < 2) ? As : Bs) + (wv & 1) * 4096;             \
    f32x4 acc[4][4];                                                           \
    _Pragma("unroll")                                                          \
    for (int i = 0; i < 4; ++i)                                                \
        _Pragma("unroll")                                                      \
        for (int j = 0; j < 4; ++j) acc[i][j] = (f32x4){0.f,0.f,0.f,0.f};      \
    const int kbeg = blockIdx.z * kchunk, kend = kbeg + kchunk;                \
    for (int kk = kbeg; kk < kend; kk += 32) {                                 \
        _Pragma("unroll")                                                      \
        for (int t = 0; t < 8; ++t) {                                          \
            const unsigned short* ga =                                         \
                smat + (size_t)(srow + t*16 + lm)*2048 + kk + lq*8;            \
            glds16(ga, sdst + t*512);                                          \
        }                                                                      \
        __syncthreads();                                                       \
        short8 ah[4], bh[4], xf[4];                                            \
        _Pragma("unroll")                                                      \
        for (int i = 0; i < 4; ++i) {                                          \
            ah[i] = *(const short8*)&As[(wm*4 + i)*512 + lane*8];              \
            bh[i] = *(const short8*)&Bs[(wn*4 + i)*512 + lane*8];              \
        }                                                                      \
        _Pragma("unroll")                                                      \
        for (int i = 0; i < 4; ++i)                                            \
            _Pragma("unroll")                                                  \
            for (int j = 0; j < 4; ++j)                                        \
                acc[i][j] = __builtin_amdgcn_mfma_f32_16x16x32_bf16(           \
                    ah[i], bh[j], acc[i][j], 0, 0, 0);                         \
        _Pragma("unroll")                                                      \
        for (int j = 0; j < 4; ++j)                                            \
            xf[j] = *(const short8*)&Bs[4096 + (wn*4 + j)*512 + lane*8];       \
        _Pragma("unroll")                                                      \
        for (int i = 0; i < 4; ++i)                                            \
            _Pragma("unroll")                                                  \
            for (int j = 0; j < 4; ++j)                                        \
                acc[i][j] = __builtin_amdgcn_mfma_f32_16x16x32_bf16(           \
                    ah[i], xf[j], acc[i][j], 0, 0, 0);                         \
        _Pragma("unroll")                                                      \
        for (int i = 0; i < 4; ++i)                                            \
            xf[i] = *(const short8*)&As[4096 + (wm*4 + i)*512 + lane*8];       \
        _Pragma("unroll")                                                      \
        for (int i = 0; i < 4; ++i)                                            \
            _Pragma("unroll")                                                  \
            for (int j = 0; j < 4; ++j)                                        \
                acc[i][j] = __builtin_amdgcn_mfma_f32_16x16x32_bf16(           \
                    xf[i], bh[j], acc[i][j], 0, 0, 0);                         \
        __syncthreads();                                                       \
    }

// Normal epilogue: C[row*ldc + col] (+ split-K partial offset).
__global__ __launch_bounds__(256) void gemm_mfma(
    const unsigned short* __restrict__ Ahi, const unsigned short* __restrict__ Alo,
    const unsigned short* __restrict__ Bhi, const unsigned short* __restrict__ Blo,
    float* __restrict__ Cbase, int ldc, int kchunk, size_t partstride)
{
    float* C = Cbase + (size_t)blockIdx.z * partstride;
    GEMM_BODY
    // C/D layout: col = lane&15, row = (lane>>4)*4 + reg
#pragma unroll
    for (int i = 0; i < 4; ++i) {
        int row = m0 + wm*64 + i*16 + lq*4;
#pragma unroll
        for (int j = 0; j < 4; ++j) {
            int col = n0 + wn*64 + j*16 + lm;
            float* cp = C + (size_t)row*ldc + col;
            cp[0*(size_t)ldc] = acc[i][j][0];
            cp[1*(size_t)ldc] = acc[i][j][1];
            cp[2*(size_t)ldc] = acc[i][j][2];
            cp[3*(size_t)ldc] = acc[i][j][3];
        }
    }
}

// Transposed epilogue: C[col*2048 + row] — reg dim (4 rows) is contiguous,
// one float4 store per (i,j) per lane. Used for ax = adj @ X^T.
__global__ __launch_bounds__(256) void gemm_mfma_T(
    const unsigned short* __restrict__ Ahi, const unsigned short* __restrict__ Alo,
    const unsigned short* __restrict__ Bhi, const unsigned short* __restrict__ Blo,
    float* __restrict__ Cbase, int kchunk, size_t partstride)
{
    float* C = Cbase + (size_t)blockIdx.z * partstride;
    GEMM_BODY
#pragma unroll
    for (int i = 0; i < 4; ++i) {
        int row = m0 + wm*64 + i*16 + lq*4;
#pragma unroll
        for (int j = 0; j < 4; ++j) {
            int col = n0 + wn*64 + j*16 + lm;
            float4 v = {acc[i][j][0], acc[i][j][1], acc[i][j][2], acc[i][j][3]};
            *(float4*)(C + (size_t)col*2048 + row) = v;
        }
    }
}

// ---------------------------------------------------------------------------
// Fused gate kernel: per block (node m, 32 rows):
//   gatesX = z_row @ Wc[64][384] + bc  (z cols b*64+g, ld = ldz; opt. zp1)
//   gatesH = h @ Whh[128][384] + bhh
//   r = sig, zg = sig, n = tanh(Xn + r*Hn), h' = (1-zg)n + zg h  (in place)
// Weights read directly from global (L2-resident); zt + h-tile staged once.
__device__ __forceinline__ float sigmoidf_(float x) {
    return 1.f / (1.f + __expf(-x));
}
__global__ __launch_bounds__(256, 4) void gxgate(
    const float* __restrict__ zbase, int ldz, const float* __restrict__ zp1,
    const float* __restrict__ Wc,  const float* __restrict__ bc,
    const float* __restrict__ Whh, const float* __restrict__ bhh,
    float* __restrict__ h)
{
    const int m  = blockIdx.x;
    const int r0 = m * 32;
    __shared__ float zt[64][36];      // [g][b]
    __shared__ float a_t[128][36];    // [k][row] full h-tile
    const int tid = threadIdx.x;
    const int cx = tid & 63;
    const int ry = tid >> 6;
    float bcv[6], bhv[6];
#pragma unroll
    for (int j = 0; j < 6; ++j) { bcv[j] = bc[cx + 64*j]; bhv[j] = bhh[cx + 64*j]; }

    {   // stage z row (optional split-K partial sum), transpose to [g][b]
        const float4* z0 = (const float4*)(zbase + (size_t)m*ldz);
        float4 u0 = z0[tid*2], u1 = z0[tid*2+1];
        if (zp1) {
            const float4* z1 = (const float4*)(zp1 + (size_t)m*ldz);
            float4 w0 = z1[tid*2], w1 = z1[tid*2+1];
            u0.x+=w0.x; u0.y+=w0.y; u0.z+=w0.z; u0.w+=w0.w;
            u1.x+=w1.x; u1.y+=w1.y; u1.z+=w1.z; u1.w+=w1.w;
        }
        int b = tid >> 3, g0 = (tid & 7) * 8;
        zt[g0+0][b] = u0.x; zt[g0+1][b] = u0.y;
        zt[g0+2][b] = u0.z; zt[g0+3][b] = u0.w;
        zt[g0+4][b] = u1.x; zt[g0+5][b] = u1.y;
        zt[g0+6][b] = u1.z; zt[g0+7][b] = u1.w;
    }
    {   // stage full h tile [128k][32r]: 1024 float4 = 256 thr x 4
#pragma unroll
        for (int p = 0; p < 4; ++p) {
            int idx = tid + 256*p;
            int lr = idx & 31, kq = idx >> 5;     // row, k-quad
            float4 v = *(const float4*)(h + (size_t)(r0+lr)*HH + kq*4);
            a_t[kq*4+0][lr] = v.x; a_t[kq*4+1][lr] = v.y;
            a_t[kq*4+2][lr] = v.z; a_t[kq*4+3][lr] = v.w;
        }
    }
    __syncthreads();

    float accx[8][6], acchn[8][2];
#pragma unroll
    for (int i = 0; i < 8; ++i) {
#pragma unroll
        for (int j = 0; j < 6; ++j) accx[i][j] = 0.f;
        acchn[i][0] = 0.f; acchn[i][1] = 0.f;
    }

    // phase 1: K=64 over Wc (x-path), a from zt (wave-uniform broadcast)
#pragma unroll 8
    for (int k = 0; k < 64; ++k) {
        float a[8];
        *(float4*)&a[0] = *(const float4*)&zt[k][ry*8];
        *(float4*)&a[4] = *(const float4*)&zt[k][ry*8+4];
        float b[6];
#pragma unroll
        for (int j = 0; j < 6; ++j) b[j] = Wc[k*384 + cx + 64*j];
#pragma unroll
        for (int i = 0; i < 8; ++i)
#pragma unroll
            for (int j = 0; j < 6; ++j)
                accx[i][j] = fmaf(a[i], b[j], accx[i][j]);
    }
    // phase 2: K=128 over Whh (h-path); r/z into accx, n separate
#pragma unroll 8
    for (int k = 0; k < HH; ++k) {
        float a[8];
        *(float4*)&a[0] = *(const float4*)&a_t[k][ry*8];
        *(float4*)&a[4] = *(const float4*)&a_t[k][ry*8+4];
        float b[6];
#pragma unroll
        for (int j = 0; j < 6; ++j) b[j] = Whh[k*384 + cx + 64*j];
#pragma unroll
        for (int i = 0; i < 8; ++i) {
#pragma unroll
            for (int j = 0; j < 4; ++j)
                accx[i][j] = fmaf(a[i], b[j], accx[i][j]);
            acchn[i][0] = fmaf(a[i], b[4], acchn[i][0]);
            acchn[i][1] = fmaf(a[i], b[5], acchn[i][1]);
        }
    }
    // epilogue: cols {cx, cx+64} of r/z/n for rows ry*8+i
#pragma unroll
    for (int i = 0; i < 8; ++i) {
        int row = r0 + ry*8 + i;
        float* hp = h + (size_t)row*HH;
        float rp0 = accx[i][0]+bcv[0]+bhv[0], rp1 = accx[i][1]+bcv[1]+bhv[1];
        float zp_0 = accx[i][2]+bcv[2]+bhv[2], zp_1 = accx[i][3]+bcv[3]+bhv[3];
        float nx0 = accx[i][4]+bcv[4],        nx1 = accx[i][5]+bcv[5];
        float nh0 = acchn[i][0]+bhv[4],       nh1 = acchn[i][1]+bhv[5];
        float h0 = hp[cx], h1 = hp[cx+64];
        float r_0 = sigmoidf_(rp0), r_1 = sigmoidf_(rp1);
        float z_0 = sigmoidf_(zp_0), z_1 = sigmoidf_(zp_1);
        float n_0 = tanhf(nx0 + r_0*nh0), n_1 = tanhf(nx1 + r_1*nh1);
        hp[cx]    = (1.f - z_0)*n_0 + z_0*h0;
        hp[cx+64] = (1.f - z_1)*n_1 + z_1*h1;
    }
}

// ---------------------------------------------------------------------------
// xfc[b][n] = h[r] . W_fc + b_fc ; also writes d_out[b][p][n]
__global__ __launch_bounds__(256) void fck(
    const float* __restrict__ h,
    const float* __restrict__ Wfc, const float* __restrict__ bfc,
    float* __restrict__ out_p,
    float* __restrict__ xfc)
{
    int w = (blockIdx.x * 256 + threadIdx.x) >> 6;
    int lane = threadIdx.x & 63;
    const float2* hr = (const float2*)(h + (size_t)w*HH);
    const float2* wf = (const float2*)Wfc;
    float2 a = hr[lane], b2 = wf[lane];
    float s = a.x*b2.x + a.y*b2.y;
#pragma unroll
    for (int off = 32; off; off >>= 1) s += __shfl_xor(s, off);
    if (lane == 0) {
        s += bfc[0];
        int n = w >> 5, b = w & 31;
        out_p[(size_t)b*(PP*NN) + n] = s;
        xfc[(size_t)b*NN + n] = s;
    }
}

// ---------------------------------------------------------------------------
extern "C" void kernel_launch(void* const* d_in, const int* in_sizes, int n_in,
                              void* d_out, int out_size, void* d_ws, size_t ws_size,
                              hipStream_t stream)
{
    const float* x    = (const float*)d_in[0];
    const float* adj  = (const float*)d_in[1];
    const float* Wg1  = (const float*)d_in[2];
    const float* bg1  = (const float*)d_in[3];
    const float* Wg2  = (const float*)d_in[4];
    const float* bg2  = (const float*)d_in[5];
    const float* Wih  = (const float*)d_in[6];
    const float* Whh  = (const float*)d_in[7];
    const float* bih  = (const float*)d_in[8];
    const float* bhh  = (const float*)d_in[9];
    const float* Wfc  = (const float*)d_in[10];
    const float* bfc  = (const float*)d_in[11];

    float* ws = (float*)d_ws;
    float* Wc   = ws;                              // 64*384
    float* bc   = Wc + GG*384;                     // 1024 (384 used)
    float* hbuf = bc + 1024;                       // RR*HH (32 MB)
    float* xfc  = hbuf + (size_t)RR*HH;            // NB*NN
    float* AXe  = xfc + (size_t)NB*NN;             // 4 partials x 384 x 2048
    float* AXd  = AXe + (size_t)4*384*NN;          // 4 partials x 128 x 2048
    float* zg   = AXd + (size_t)4*128*NN;          // 3*2048*2048 (48 MB)
    unsigned short* Ahi  = (unsigned short*)(zg + (size_t)3*NN*NN);
    unsigned short* Alo  = Ahi  + (size_t)NN*NN;
    unsigned short* Xehi = Alo  + (size_t)NN*NN;   // 384 x 2048
    unsigned short* Xelo = Xehi + (size_t)384*NN;
    unsigned short* Xdhi = Xelo + (size_t)384*NN;  // 128 x 2048
    unsigned short* Xdlo = Xdhi + (size_t)128*NN;
    unsigned short* Hghi = Xdlo + (size_t)128*NN;  // 6144 x 2048 (24 MB)
    unsigned short* Hglo = Hghi + (size_t)6144*NN;
    // total ws use ~172 MiB

    hipMemsetAsync(hbuf, 0, (size_t)RR*HH*sizeof(float), stream);
    // zero decoder X pad rows 32..127 (persist across the launch)
    hipMemsetAsync(Xdhi + (size_t)32*NN, 0, (size_t)96*NN*sizeof(unsigned short), stream);
    hipMemsetAsync(Xdlo + (size_t)32*NN, 0, (size_t)96*NN*sizeof(unsigned short), stream);

    splitk<<<2048, 256, 0, stream>>>(adj, Ahi, Alo);
    wprep<<<98, 256, 0, stream>>>(Wg2, Wih, bih, bg2, Wc, bc);
    xsplit_enc<<<384, 256, 0, stream>>>(x, Xehi, Xelo);
    // encoder ax = adj @ Xe^T, all 12 steps at once (split-K 4, transposed C)
    gemm_mfma_T<<<dim3(3, 16, 4), 256, 0, stream>>>(
        Ahi, Alo, Xehi, Xelo, AXe, 512, (size_t)384*NN);

    float* outp = (float*)d_out;

    // encoder: 4 groups of 3 steps; z-GEMM batched per group (N=6144 cols)
    for (int g = 0; g < 4; ++g) {
        h1T<<<dim3(NN, 3), 256, 0, stream>>>(
            AXe, g*96, (size_t)384*NN, Wg1, bg1, Hghi, Hglo);
        gemm_mfma<<<dim3(48, 16, 1), 256, 0, stream>>>(
            Ahi, Alo, Hghi, Hglo, zg, 6144, 2048, 0);
        for (int ty = 0; ty < 3; ++ty)
            gxgate<<<NN, 256, 0, stream>>>(
                zg + ty*NN, 6144, nullptr, Wc, bc, Whh, bhh, hbuf);
    }
    // decoder
    for (int p = 0; p < PP; ++p) {
        fck<<<RR/4, 256, 0, stream>>>(hbuf, Wfc, bfc, outp + (size_t)p*NN, xfc);
        if (p < PP-1) {
            xsplit_dec<<<32, 256, 0, stream>>>(xfc, Xdhi, Xdlo);
            gemm_mfma_T<<<dim3(1, 16, 4), 256, 0, stream>>>(
                Ahi, Alo, Xdhi, Xdlo, AXd, 512, (size_t)128*NN);
            h1T<<<dim3(NN, 1), 256, 0, stream>>>(
                AXd, 0, (size_t)128*NN, Wg1, bg1, Hghi, Hglo);
            gemm_mfma<<<dim3(16, 16, 2), 256, 0, stream>>>(
                Ahi, Alo, Hghi, Hglo, zg, 2048, 1024, (size_t)NN*NN);
            gxgate<<<NN, 256, 0, stream>>>(
                zg, 2048, zg + (size_t)NN*NN, Wc, bc, Whh, bhh, hbuf);
        }
    }
}

// Round 7
// 2837.681 us; speedup vs baseline: 3.5695x; 1.1318x over previous
//
#include <hip/hip_runtime.h>
#include <math.h>

// Problem constants: B=32, S=12, N=2048, F=1, H=128, G=64, O=1, P=3
#define NB 32
#define SS 12
#define NN 2048
#define HH 128
#define GG 64
#define PP 3
#define RR (NN*NB)   // 65536 rows, node-major r = n*32 + b

typedef __attribute__((ext_vector_type(8))) _Float16 half8;  // 8 fp16 (4 VGPRs)
typedef __attribute__((ext_vector_type(4))) float f32x4;

__device__ __forceinline__ void glds16(const void* g, const void* l) {
    __builtin_amdgcn_global_load_lds(
        (const __attribute__((address_space(1))) void*)g,
        (__attribute__((address_space(3))) void*)l, 16, 0, 0);
}

// ---------------------------------------------------------------------------
// fp32 -> fp16 (RNE via v_cvt_f16_f32), 8 elems/thread
__global__ __launch_bounds__(256) void cvtadj(
    const float* __restrict__ src, _Float16* __restrict__ dst)
{
    size_t i0 = ((size_t)blockIdx.x * 256 + threadIdx.x) * 8;
    float4 v0 = *(const float4*)(src + i0);
    float4 v1 = *(const float4*)(src + i0 + 4);
    union { _Float16 h[8]; uint4 q; } H;
    H.h[0]=(_Float16)v0.x; H.h[1]=(_Float16)v0.y;
    H.h[2]=(_Float16)v0.z; H.h[3]=(_Float16)v0.w;
    H.h[4]=(_Float16)v1.x; H.h[5]=(_Float16)v1.y;
    H.h[6]=(_Float16)v1.z; H.h[7]=(_Float16)v1.w;
    *(uint4*)(dst + i0) = H.q;
}

// ---------------------------------------------------------------------------
// Encoder x -> fp16 rows [(t*32+b)][n] from x[b][t][n]. 384 blocks.
__global__ __launch_bounds__(256) void xcvt_enc(
    const float* __restrict__ x, _Float16* __restrict__ dst)
{
    const int row = blockIdx.x;            // t*32 + b
    const int t = row >> 5, b = row & 31;
    const size_t n0 = (size_t)threadIdx.x * 8;
    const float* src = x + ((size_t)b*SS + t)*NN;
    float4 v0 = *(const float4*)(src + n0);
    float4 v1 = *(const float4*)(src + n0 + 4);
    union { _Float16 h[8]; uint4 q; } H;
    H.h[0]=(_Float16)v0.x; H.h[1]=(_Float16)v0.y;
    H.h[2]=(_Float16)v0.z; H.h[3]=(_Float16)v0.w;
    H.h[4]=(_Float16)v1.x; H.h[5]=(_Float16)v1.y;
    H.h[6]=(_Float16)v1.z; H.h[7]=(_Float16)v1.w;
    *(uint4*)(dst + (size_t)row*NN + n0) = H.q;
}

// Decoder xfc[b][n] -> fp16 rows [b][n] (rows 32..127 pre-zeroed). 32 blocks.
__global__ __launch_bounds__(256) void xcvt_dec(
    const float* __restrict__ xfc, _Float16* __restrict__ dst)
{
    const int b = blockIdx.x;
    const size_t n0 = (size_t)threadIdx.x * 8;
    const float* src = xfc + (size_t)b*NN;
    float4 v0 = *(const float4*)(src + n0);
    float4 v1 = *(const float4*)(src + n0 + 4);
    union { _Float16 h[8]; uint4 q; } H;
    H.h[0]=(_Float16)v0.x; H.h[1]=(_Float16)v0.y;
    H.h[2]=(_Float16)v0.z; H.h[3]=(_Float16)v0.w;
    H.h[4]=(_Float16)v1.x; H.h[5]=(_Float16)v1.y;
    H.h[6]=(_Float16)v1.z; H.h[7]=(_Float16)v1.w;
    *(uint4*)(dst + (size_t)b*NN + n0) = H.q;
}

// ---------------------------------------------------------------------------
// Precompute Wc[64][384] = Wg2 @ Wih and bc[384] = bg2 @ Wih + bih.
__global__ __launch_bounds__(256) void wprep(
    const float* __restrict__ Wg2, const float* __restrict__ Wih,
    const float* __restrict__ bih, const float* __restrict__ bg2,
    float* __restrict__ Wc, float* __restrict__ bc)
{
    int idx = blockIdx.x * 256 + threadIdx.x;
    if (idx < GG*384) {
        int g = idx / 384, o = idx % 384;
        float s = 0.f;
        for (int k = 0; k < HH; ++k)
            s = fmaf(Wg2[g*HH + k], Wih[k*384 + o], s);
        Wc[idx] = s;
    } else if (idx < GG*384 + 384) {
        int o = idx - GG*384;
        float s = bih[o];
        for (int k = 0; k < HH; ++k)
            s = fmaf(bg2[k], Wih[k*384 + o], s);
        bc[o] = s;
    }
}

// ---------------------------------------------------------------------------
// h1 from ax partials: H[(ty*2048 + c)][n] = fp16(relu(ax[.]*W1[g]+b1[g])),
// c = b*64+g; ax row = col_base + ty*32 + b, summed over 4 split-K partials.
__global__ __launch_bounds__(256) void h1T(
    const float* __restrict__ axpart, int col_base, size_t part_stride,
    const float* __restrict__ Wg1, const float* __restrict__ bg1,
    _Float16* __restrict__ Hh)
{
    const int c = blockIdx.x;
    const int ty = blockIdx.y;
    const int b = c >> 6, g = c & 63;
    const float w1 = Wg1[g], b1 = bg1[g];
    const size_t n0 = (size_t)threadIdx.x * 8;
    const size_t rowoff = (size_t)(col_base + ty*32 + b) * NN + n0;
    float f[8] = {0,0,0,0,0,0,0,0};
#pragma unroll
    for (int p = 0; p < 4; ++p) {
        const float4* q = (const float4*)(axpart + p*part_stride + rowoff);
        float4 v0 = q[0], v1 = q[1];
        f[0]+=v0.x; f[1]+=v0.y; f[2]+=v0.z; f[3]+=v0.w;
        f[4]+=v1.x; f[5]+=v1.y; f[6]+=v1.z; f[7]+=v1.w;
    }
    union { _Float16 h[8]; uint4 q; } H;
#pragma unroll
    for (int k = 0; k < 8; ++k)
        H.h[k] = (_Float16)fmaxf(fmaf(f[k], w1, b1), 0.f);
    *(uint4*)(Hh + ((size_t)ty*2048 + c) * NN + n0) = H.q;
}

// ---------------------------------------------------------------------------
// Plain fp16 MFMA GEMM (m97 structure): C = A @ B^T, A[2048 rows m][K],
// B[cols][K], both fp16 row-major k-contiguous. 128x128 tile, BK=64,
// global_load_lds 16B in fragment order, 16x16x32 MFMA, fp32 acc.
// kchunk = logical K per blockIdx.z (split-K).
#define GEMM_BODY                                                              \
    __shared__ __align__(16) _Float16 As[8192];  /* 16 tiles x (16m x 32k) */  \
    __shared__ __align__(16) _Float16 Bs[8192];                                \
    const int tid  = threadIdx.x;                                              \
    const int wv   = tid >> 6, lane = tid & 63;                                \
    const int lm   = lane & 15, lq = lane >> 4;                                \
    const int m0   = blockIdx.y * 128;                                         \
    const int n0   = blockIdx.x * 128;                                         \
    const int wm   = wv >> 1, wn = wv & 1;                                     \
    f32x4 acc[4][4];                                                           \
    _Pragma("unroll")                                                          \
    for (int i = 0; i < 4; ++i)                                                \
        _Pragma("unroll")                                                      \
        for (int j = 0; j < 4; ++j) acc[i][j] = (f32x4){0.f,0.f,0.f,0.f};      \
    const int kbeg = blockIdx.z * kchunk, kend = kbeg + kchunk;                \
    for (int k0 = kbeg; k0 < kend; k0 += 64) {                                 \
        _Pragma("unroll")                                                      \
        for (int t = 0; t < 4; ++t) {                                          \
            int tt = wv*4 + t;                                                 \
            int rt = tt >> 1, kt = tt & 1;                                     \
            glds16(Ah + (size_t)(m0 + rt*16 + lm)*2048 + k0 + kt*32 + lq*8,    \
                   &As[tt*512]);                                               \
            glds16(Bh + (size_t)(n0 + rt*16 + lm)*2048 + k0 + kt*32 + lq*8,    \
                   &Bs[tt*512]);                                               \
        }                                                                      \
        __syncthreads();                                                       \
        _Pragma("unroll")                                                      \
        for (int ks = 0; ks < 2; ++ks) {                                       \
            half8 af[4], bf[4];                                                \
            _Pragma("unroll")                                                  \
            for (int i = 0; i < 4; ++i) {                                      \
                af[i] = *(const half8*)&As[((wm*4 + i)*2 + ks)*512 + lane*8];  \
                bf[i] = *(const half8*)&Bs[((wn*4 + i)*2 + ks)*512 + lane*8];  \
            }                                                                  \
            _Pragma("unroll")                                                  \
            for (int i = 0; i < 4; ++i)                                        \
                _Pragma("unroll")                                              \
                for (int j = 0; j < 4; ++j)                                    \
                    acc[i][j] = __builtin_amdgcn_mfma_f32_16x16x32_f16(        \
                        af[i], bf[j], acc[i][j], 0, 0, 0);                     \
        }                                                                      \
        __syncthreads();                                                       \
    }

// Normal epilogue: C[row*ldc + col] (+ split-K partial offset).
__global__ __launch_bounds__(256) void gemm_mfma(
    const _Float16* __restrict__ Ah, const _Float16* __restrict__ Bh,
    float* __restrict__ Cbase, int ldc, int kchunk, size_t partstride)
{
    float* C = Cbase + (size_t)blockIdx.z * partstride;
    GEMM_BODY
    // C/D layout: col = lane&15, row = (lane>>4)*4 + reg
#pragma unroll
    for (int i = 0; i < 4; ++i) {
        int row = m0 + wm*64 + i*16 + lq*4;
#pragma unroll
        for (int j = 0; j < 4; ++j) {
            int col = n0 + wn*64 + j*16 + lm;
            float* cp = C + (size_t)row*ldc + col;
            cp[0*(size_t)ldc] = acc[i][j][0];
            cp[1*(size_t)ldc] = acc[i][j][1];
            cp[2*(size_t)ldc] = acc[i][j][2];
            cp[3*(size_t)ldc] = acc[i][j][3];
        }
    }
}

// Transposed epilogue: C[col*2048 + row] — reg dim (4 rows) contiguous,
// one float4 store per (i,j) per lane. Used for ax = adj @ X^T.
__global__ __launch_bounds__(256) void gemm_mfma_T(
    const _Float16* __restrict__ Ah, const _Float16* __restrict__ Bh,
    float* __restrict__ Cbase, int kchunk, size_t partstride)
{
    float* C = Cbase + (size_t)blockIdx.z * partstride;
    GEMM_BODY
#pragma unroll
    for (int i = 0; i < 4; ++i) {
        int row = m0 + wm*64 + i*16 + lq*4;
#pragma unroll
        for (int j = 0; j < 4; ++j) {
            int col = n0 + wn*64 + j*16 + lm;
            float4 v = {acc[i][j][0], acc[i][j][1], acc[i][j][2], acc[i][j][3]};
            *(float4*)(C + (size_t)col*2048 + row) = v;
        }
    }
}

// ---------------------------------------------------------------------------
// Fused gate kernel: per block (node m, 32 rows):
//   gatesX = z_row @ Wc[64][384] + bc  (z cols b*64+g, ld = ldz; opt. zp1)
//   gatesH = h @ Whh[128][384] + bhh
//   r = sig, zg = sig, n = tanh(Xn + r*Hn), h' = (1-zg)n + zg h  (in place)
// Weights read directly from global (L2-resident); zt + h-tile staged once.
__device__ __forceinline__ float sigmoidf_(float x) {
    return 1.f / (1.f + __expf(-x));
}
__global__ __launch_bounds__(256, 4) void gxgate(
    const float* __restrict__ zbase, int ldz, const float* __restrict__ zp1,
    const float* __restrict__ Wc,  const float* __restrict__ bc,
    const float* __restrict__ Whh, const float* __restrict__ bhh,
    float* __restrict__ h)
{
    const int m  = blockIdx.x;
    const int r0 = m * 32;
    __shared__ float zt[64][36];      // [g][b]
    __shared__ float a_t[128][36];    // [k][row] full h-tile
    const int tid = threadIdx.x;
    const int cx = tid & 63;
    const int ry = tid >> 6;
    float bcv[6], bhv[6];
#pragma unroll
    for (int j = 0; j < 6; ++j) { bcv[j] = bc[cx + 64*j]; bhv[j] = bhh[cx + 64*j]; }

    {   // stage z row (optional split-K partial sum), transpose to [g][b]
        const float4* z0 = (const float4*)(zbase + (size_t)m*ldz);
        float4 u0 = z0[tid*2], u1 = z0[tid*2+1];
        if (zp1) {
            const float4* z1 = (const float4*)(zp1 + (size_t)m*ldz);
            float4 w0 = z1[tid*2], w1 = z1[tid*2+1];
            u0.x+=w0.x; u0.y+=w0.y; u0.z+=w0.z; u0.w+=w0.w;
            u1.x+=w1.x; u1.y+=w1.y; u1.z+=w1.z; u1.w+=w1.w;
        }
        int b = tid >> 3, g0 = (tid & 7) * 8;
        zt[g0+0][b] = u0.x; zt[g0+1][b] = u0.y;
        zt[g0+2][b] = u0.z; zt[g0+3][b] = u0.w;
        zt[g0+4][b] = u1.x; zt[g0+5][b] = u1.y;
        zt[g0+6][b] = u1.z; zt[g0+7][b] = u1.w;
    }
    {   // stage full h tile [128k][32r]: 1024 float4 = 256 thr x 4
#pragma unroll
        for (int p = 0; p < 4; ++p) {
            int idx = tid + 256*p;
            int lr = idx & 31, kq = idx >> 5;     // row, k-quad
            float4 v = *(const float4*)(h + (size_t)(r0+lr)*HH + kq*4);
            a_t[kq*4+0][lr] = v.x; a_t[kq*4+1][lr] = v.y;
            a_t[kq*4+2][lr] = v.z; a_t[kq*4+3][lr] = v.w;
        }
    }
    __syncthreads();

    float accx[8][6], acchn[8][2];
#pragma unroll
    for (int i = 0; i < 8; ++i) {
#pragma unroll
        for (int j = 0; j < 6; ++j) accx[i][j] = 0.f;
        acchn[i][0] = 0.f; acchn[i][1] = 0.f;
    }

    // phase 1: K=64 over Wc (x-path), a from zt (wave-uniform broadcast)
#pragma unroll 8
    for (int k = 0; k < 64; ++k) {
        float a[8];
        *(float4*)&a[0] = *(const float4*)&zt[k][ry*8];
        *(float4*)&a[4] = *(const float4*)&zt[k][ry*8+4];
        float b[6];
#pragma unroll
        for (int j = 0; j < 6; ++j) b[j] = Wc[k*384 + cx + 64*j];
#pragma unroll
        for (int i = 0; i < 8; ++i)
#pragma unroll
            for (int j = 0; j < 6; ++j)
                accx[i][j] = fmaf(a[i], b[j], accx[i][j]);
    }
    // phase 2: K=128 over Whh (h-path); r/z into accx, n separate
#pragma unroll 8
    for (int k = 0; k < HH; ++k) {
        float a[8];
        *(float4*)&a[0] = *(const float4*)&a_t[k][ry*8];
        *(float4*)&a[4] = *(const float4*)&a_t[k][ry*8+4];
        float b[6];
#pragma unroll
        for (int j = 0; j < 6; ++j) b[j] = Whh[k*384 + cx + 64*j];
#pragma unroll
        for (int i = 0; i < 8; ++i) {
#pragma unroll
            for (int j = 0; j < 4; ++j)
                accx[i][j] = fmaf(a[i], b[j], accx[i][j]);
            acchn[i][0] = fmaf(a[i], b[4], acchn[i][0]);
            acchn[i][1] = fmaf(a[i], b[5], acchn[i][1]);
        }
    }
    // epilogue: cols {cx, cx+64} of r/z/n for rows ry*8+i
#pragma unroll
    for (int i = 0; i < 8; ++i) {
        int row = r0 + ry*8 + i;
        float* hp = h + (size_t)row*HH;
        float rp0 = accx[i][0]+bcv[0]+bhv[0], rp1 = accx[i][1]+bcv[1]+bhv[1];
        float zp_0 = accx[i][2]+bcv[2]+bhv[2], zp_1 = accx[i][3]+bcv[3]+bhv[3];
        float nx0 = accx[i][4]+bcv[4],        nx1 = accx[i][5]+bcv[5];
        float nh0 = acchn[i][0]+bhv[4],       nh1 = acchn[i][1]+bhv[5];
        float h0 = hp[cx], h1 = hp[cx+64];
        float r_0 = sigmoidf_(rp0), r_1 = sigmoidf_(rp1);
        float z_0 = sigmoidf_(zp_0), z_1 = sigmoidf_(zp_1);
        float n_0 = tanhf(nx0 + r_0*nh0), n_1 = tanhf(nx1 + r_1*nh1);
        hp[cx]    = (1.f - z_0)*n_0 + z_0*h0;
        hp[cx+64] = (1.f - z_1)*n_1 + z_1*h1;
    }
}

// ---------------------------------------------------------------------------
// xfc[b][n] = h[r] . W_fc + b_fc ; also writes d_out[b][p][n]
__global__ __launch_bounds__(256) void fck(
    const float* __restrict__ h,
    const float* __restrict__ Wfc, const float* __restrict__ bfc,
    float* __restrict__ out_p,
    float* __restrict__ xfc)
{
    int w = (blockIdx.x * 256 + threadIdx.x) >> 6;
    int lane = threadIdx.x & 63;
    const float2* hr = (const float2*)(h + (size_t)w*HH);
    const float2* wf = (const float2*)Wfc;
    float2 a = hr[lane], b2 = wf[lane];
    float s = a.x*b2.x + a.y*b2.y;
#pragma unroll
    for (int off = 32; off; off >>= 1) s += __shfl_xor(s, off);
    if (lane == 0) {
        s += bfc[0];
        int n = w >> 5, b = w & 31;
        out_p[(size_t)b*(PP*NN) + n] = s;
        xfc[(size_t)b*NN + n] = s;
    }
}

// ---------------------------------------------------------------------------
extern "C" void kernel_launch(void* const* d_in, const int* in_sizes, int n_in,
                              void* d_out, int out_size, void* d_ws, size_t ws_size,
                              hipStream_t stream)
{
    const float* x    = (const float*)d_in[0];
    const float* adj  = (const float*)d_in[1];
    const float* Wg1  = (const float*)d_in[2];
    const float* bg1  = (const float*)d_in[3];
    const float* Wg2  = (const float*)d_in[4];
    const float* bg2  = (const float*)d_in[5];
    const float* Wih  = (const float*)d_in[6];
    const float* Whh  = (const float*)d_in[7];
    const float* bih  = (const float*)d_in[8];
    const float* bhh  = (const float*)d_in[9];
    const float* Wfc  = (const float*)d_in[10];
    const float* bfc  = (const float*)d_in[11];

    float* ws = (float*)d_ws;
    float* Wc   = ws;                              // 64*384
    float* bc   = Wc + GG*384;                     // 1024 (384 used)
    float* hbuf = bc + 1024;                       // RR*HH (32 MB)
    float* xfc  = hbuf + (size_t)RR*HH;            // NB*NN
    float* AXe  = xfc + (size_t)NB*NN;             // 4 partials x 384 x 2048
    float* AXd  = AXe + (size_t)4*384*NN;          // 4 partials x 128 x 2048
    float* zg   = AXd + (size_t)4*128*NN;          // 3*2048*2048 (48 MB)
    _Float16* Ah  = (_Float16*)(zg + (size_t)3*NN*NN);  // 2048 x 2048 (8 MB)
    _Float16* Xeh = Ah  + (size_t)NN*NN;           // 384 x 2048
    _Float16* Xdh = Xeh + (size_t)384*NN;          // 128 x 2048
    _Float16* Hgh = Xdh + (size_t)128*NN;          // 6144 x 2048 (24 MB)
    // total ws use ~130 MiB

    hipMemsetAsync(hbuf, 0, (size_t)RR*HH*sizeof(float), stream);
    // zero decoder X pad rows 32..127 (persist across the launch)
    hipMemsetAsync(Xdh + (size_t)32*NN, 0, (size_t)96*NN*sizeof(_Float16), stream);

    cvtadj<<<2048, 256, 0, stream>>>(adj, Ah);
    wprep<<<98, 256, 0, stream>>>(Wg2, Wih, bih, bg2, Wc, bc);
    xcvt_enc<<<384, 256, 0, stream>>>(x, Xeh);
    // encoder ax = adj @ Xe^T, all 12 steps at once (split-K 4, transposed C)
    gemm_mfma_T<<<dim3(3, 16, 4), 256, 0, stream>>>(
        Ah, Xeh, AXe, 512, (size_t)384*NN);

    float* outp = (float*)d_out;

    // encoder: 4 groups of 3 steps; z-GEMM batched per group (N=6144 cols)
    for (int g = 0; g < 4; ++g) {
        h1T<<<dim3(NN, 3), 256, 0, stream>>>(
            AXe, g*96, (size_t)384*NN, Wg1, bg1, Hgh);
        gemm_mfma<<<dim3(48, 16, 1), 256, 0, stream>>>(
            Ah, Hgh, zg, 6144, 2048, 0);
        for (int ty = 0; ty < 3; ++ty)
            gxgate<<<NN, 256, 0, stream>>>(
                zg + ty*NN, 6144, nullptr, Wc, bc, Whh, bhh, hbuf);
    }
    // decoder
    for (int p = 0; p < PP; ++p) {
        fck<<<RR/4, 256, 0, stream>>>(hbuf, Wfc, bfc, outp + (size_t)p*NN, xfc);
        if (p < PP-1) {
            xcvt_dec<<<32, 256, 0, stream>>>(xfc, Xdh);
            gemm_mfma_T<<<dim3(1, 16, 4), 256, 0, stream>>>(
                Ah, Xdh, AXd, 512, (size_t)128*NN);
            h1T<<<dim3(NN, 1), 256, 0, stream>>>(
                AXd, 0, (size_t)128*NN, Wg1, bg1, Hgh);
            gemm_mfma<<<dim3(16, 16, 2), 256, 0, stream>>>(
                Ah, Hgh, zg, 2048, 1024, (size_t)NN*NN);
            gxgate<<<NN, 256, 0, stream>>>(
                zg, 2048, zg + (size_t)NN*NN, Wc, bc, Whh, bhh, hbuf);
        }
    }
}

// Round 8
// 1386.656 us; speedup vs baseline: 7.3048x; 2.0464x over previous
//
#include <hip/hip_runtime.h>
#include <math.h>

// Problem constants: B=32, S=12, N=2048, F=1, H=128, G=64, O=1, P=3
#define NB 32
#define SS 12
#define NN 2048
#define HH 128
#define GG 64
#define PP 3
#define RR (NN*NB)   // 65536 rows, node-major r = n*32 + b

typedef __attribute__((ext_vector_type(8))) _Float16 half8;  // 8 fp16 (4 VGPRs)
typedef __attribute__((ext_vector_type(4))) float f32x4;

__device__ __forceinline__ void glds16(const void* g, const void* l) {
    __builtin_amdgcn_global_load_lds(
        (const __attribute__((address_space(1))) void*)g,
        (__attribute__((address_space(3))) void*)l, 16, 0, 0);
}

// ---------------------------------------------------------------------------
// fp32 -> fp16 (RNE), 8 elems/thread
__global__ __launch_bounds__(256) void cvtadj(
    const float* __restrict__ src, _Float16* __restrict__ dst)
{
    size_t i0 = ((size_t)blockIdx.x * 256 + threadIdx.x) * 8;
    float4 v0 = *(const float4*)(src + i0);
    float4 v1 = *(const float4*)(src + i0 + 4);
    union { _Float16 h[8]; uint4 q; } H;
    H.h[0]=(_Float16)v0.x; H.h[1]=(_Float16)v0.y;
    H.h[2]=(_Float16)v0.z; H.h[3]=(_Float16)v0.w;
    H.h[4]=(_Float16)v1.x; H.h[5]=(_Float16)v1.y;
    H.h[6]=(_Float16)v1.z; H.h[7]=(_Float16)v1.w;
    *(uint4*)(dst + i0) = H.q;
}

// Encoder x -> fp16 rows [(t*32+b)][n] from x[b][t][n]. 384 blocks.
__global__ __launch_bounds__(256) void xcvt_enc(
    const float* __restrict__ x, _Float16* __restrict__ dst)
{
    const int row = blockIdx.x;            // t*32 + b
    const int t = row >> 5, b = row & 31;
    const size_t n0 = (size_t)threadIdx.x * 8;
    const float* src = x + ((size_t)b*SS + t)*NN;
    float4 v0 = *(const float4*)(src + n0);
    float4 v1 = *(const float4*)(src + n0 + 4);
    union { _Float16 h[8]; uint4 q; } H;
    H.h[0]=(_Float16)v0.x; H.h[1]=(_Float16)v0.y;
    H.h[2]=(_Float16)v0.z; H.h[3]=(_Float16)v0.w;
    H.h[4]=(_Float16)v1.x; H.h[5]=(_Float16)v1.y;
    H.h[6]=(_Float16)v1.z; H.h[7]=(_Float16)v1.w;
    *(uint4*)(dst + (size_t)row*NN + n0) = H.q;
}

// Decoder xfc[b][n] -> fp16 rows [b][n] (rows 32..127 pre-zeroed). 32 blocks.
__global__ __launch_bounds__(256) void xcvt_dec(
    const float* __restrict__ xfc, _Float16* __restrict__ dst)
{
    const int b = blockIdx.x;
    const size_t n0 = (size_t)threadIdx.x * 8;
    const float* src = xfc + (size_t)b*NN;
    float4 v0 = *(const float4*)(src + n0);
    float4 v1 = *(const float4*)(src + n0 + 4);
    union { _Float16 h[8]; uint4 q; } H;
    H.h[0]=(_Float16)v0.x; H.h[1]=(_Float16)v0.y;
    H.h[2]=(_Float16)v0.z; H.h[3]=(_Float16)v0.w;
    H.h[4]=(_Float16)v1.x; H.h[5]=(_Float16)v1.y;
    H.h[6]=(_Float16)v1.z; H.h[7]=(_Float16)v1.w;
    *(uint4*)(dst + (size_t)b*NN + n0) = H.q;
}

// ---------------------------------------------------------------------------
// Precompute Wc[64][384] = Wg2 @ Wih and bc[384] = bg2 @ Wih + bih.
__global__ __launch_bounds__(256) void wprep(
    const float* __restrict__ Wg2, const float* __restrict__ Wih,
    const float* __restrict__ bih, const float* __restrict__ bg2,
    float* __restrict__ Wc, float* __restrict__ bc)
{
    int idx = blockIdx.x * 256 + threadIdx.x;
    if (idx < GG*384) {
        int g = idx / 384, o = idx % 384;
        float s = 0.f;
        for (int k = 0; k < HH; ++k)
            s = fmaf(Wg2[g*HH + k], Wih[k*384 + o], s);
        Wc[idx] = s;
    } else if (idx < GG*384 + 384) {
        int o = idx - GG*384;
        float s = bih[o];
        for (int k = 0; k < HH; ++k)
            s = fmaf(bg2[k], Wih[k*384 + o], s);
        bc[o] = s;
    }
}

// Wcomb[o][k] fp16 (o=0..383, k=0..191): k<64 -> Wc[k][o], else Whh[k-64][o].
__global__ __launch_bounds__(256) void wprep2(
    const float* __restrict__ Wc, const float* __restrict__ Whh,
    _Float16* __restrict__ Wcomb)
{
    int idx = blockIdx.x * 256 + threadIdx.x;
    if (idx < 384*192) {
        int o = idx / 192, k = idx % 192;
        float v = (k < 64) ? Wc[k*384 + o] : Whh[(k-64)*384 + o];
        Wcomb[idx] = (_Float16)v;
    }
}

// ---------------------------------------------------------------------------
// h1 from ax partials: H[(ty*2048 + c)][n] = fp16(relu(ax[.]*W1[g]+b1[g])),
// c = b*64+g; ax row = col_base + ty*32 + b, summed over 4 split-K partials.
__global__ __launch_bounds__(256) void h1T(
    const float* __restrict__ axpart, int col_base, size_t part_stride,
    const float* __restrict__ Wg1, const float* __restrict__ bg1,
    _Float16* __restrict__ Hh)
{
    const int c = blockIdx.x;
    const int ty = blockIdx.y;
    const int b = c >> 6, g = c & 63;
    const float w1 = Wg1[g], b1 = bg1[g];
    const size_t n0 = (size_t)threadIdx.x * 8;
    const size_t rowoff = (size_t)(col_base + ty*32 + b) * NN + n0;
    float f[8] = {0,0,0,0,0,0,0,0};
#pragma unroll
    for (int p = 0; p < 4; ++p) {
        const float4* q = (const float4*)(axpart + p*part_stride + rowoff);
        float4 v0 = q[0], v1 = q[1];
        f[0]+=v0.x; f[1]+=v0.y; f[2]+=v0.z; f[3]+=v0.w;
        f[4]+=v1.x; f[5]+=v1.y; f[6]+=v1.z; f[7]+=v1.w;
    }
    union { _Float16 h[8]; uint4 q; } H;
#pragma unroll
    for (int k = 0; k < 8; ++k)
        H.h[k] = (_Float16)fmaxf(fmaf(f[k], w1, b1), 0.f);
    *(uint4*)(Hh + ((size_t)ty*2048 + c) * NN + n0) = H.q;
}

// ---------------------------------------------------------------------------
// Plain fp16 MFMA GEMM (m97 structure): C = A @ B^T, A[m][K], B[cols][K],
// fp16 k-contiguous. 128x128 tile, BK=64, global_load_lds 16B, 16x16x32 MFMA.
#define GEMM_BODY                                                              \
    __shared__ __align__(16) _Float16 As[8192];  /* 16 tiles x (16m x 32k) */  \
    __shared__ __align__(16) _Float16 Bs[8192];                                \
    const int tid  = threadIdx.x;                                              \
    const int wv   = tid >> 6, lane = tid & 63;                                \
    const int lm   = lane & 15, lq = lane >> 4;                                \
    const int m0   = blockIdx.y * 128;                                         \
    const int n0   = blockIdx.x * 128;                                         \
    const int wm   = wv >> 1, wn = wv & 1;                                     \
    f32x4 acc[4][4];                                                           \
    _Pragma("unroll")                                                          \
    for (int i = 0; i < 4; ++i)                                                \
        _Pragma("unroll")                                                      \
        for (int j = 0; j < 4; ++j) acc[i][j] = (f32x4){0.f,0.f,0.f,0.f};      \
    const int kbeg = blockIdx.z * kchunk, kend = kbeg + kchunk;                \
    for (int k0 = kbeg; k0 < kend; k0 += 64) {                                 \
        _Pragma("unroll")                                                      \
        for (int t = 0; t < 4; ++t) {                                          \
            int tt = wv*4 + t;                                                 \
            int rt = tt >> 1, kt = tt & 1;                                     \
            glds16(Ah + (size_t)(m0 + rt*16 + lm)*2048 + k0 + kt*32 + lq*8,    \
                   &As[tt*512]);                                               \
            glds16(Bh + (size_t)(n0 + rt*16 + lm)*2048 + k0 + kt*32 + lq*8,    \
                   &Bs[tt*512]);                                               \
        }                                                                      \
        __syncthreads();                                                       \
        _Pragma("unroll")                                                      \
        for (int ks = 0; ks < 2; ++ks) {                                       \
            half8 af[4], bf[4];                                                \
            _Pragma("unroll")                                                  \
            for (int i = 0; i < 4; ++i) {                                      \
                af[i] = *(const half8*)&As[((wm*4 + i)*2 + ks)*512 + lane*8];  \
                bf[i] = *(const half8*)&Bs[((wn*4 + i)*2 + ks)*512 + lane*8];  \
            }                                                                  \
            _Pragma("unroll")                                                  \
            for (int i = 0; i < 4; ++i)                                        \
                _Pragma("unroll")                                              \
                for (int j = 0; j < 4; ++j)                                    \
                    acc[i][j] = __builtin_amdgcn_mfma_f32_16x16x32_f16(        \
                        af[i], bf[j], acc[i][j], 0, 0, 0);                     \
        }                                                                      \
        __syncthreads();                                                       \
    }

// fp16-C epilogue: C[row*ldc + col] (z-GEMM; consumed by gatemm as fp16 A).
__global__ __launch_bounds__(256) void gemm_mfma(
    const _Float16* __restrict__ Ah, const _Float16* __restrict__ Bh,
    _Float16* __restrict__ C, int ldc, int kchunk)
{
    GEMM_BODY
    // C/D layout: col = lane&15, row = (lane>>4)*4 + reg
#pragma unroll
    for (int i = 0; i < 4; ++i) {
        int row = m0 + wm*64 + i*16 + lq*4;
#pragma unroll
        for (int j = 0; j < 4; ++j) {
            int col = n0 + wn*64 + j*16 + lm;
            _Float16* cp = C + (size_t)row*ldc + col;
            cp[0*(size_t)ldc] = (_Float16)acc[i][j][0];
            cp[1*(size_t)ldc] = (_Float16)acc[i][j][1];
            cp[2*(size_t)ldc] = (_Float16)acc[i][j][2];
            cp[3*(size_t)ldc] = (_Float16)acc[i][j][3];
        }
    }
}

// Transposed fp32 epilogue: C[col*2048 + row], float4 per (i,j). ax = adj@X^T.
__global__ __launch_bounds__(256) void gemm_mfma_T(
    const _Float16* __restrict__ Ah, const _Float16* __restrict__ Bh,
    float* __restrict__ Cbase, int kchunk, size_t partstride)
{
    float* C = Cbase + (size_t)blockIdx.z * partstride;
    GEMM_BODY
#pragma unroll
    for (int i = 0; i < 4; ++i) {
        int row = m0 + wm*64 + i*16 + lq*4;
#pragma unroll
        for (int j = 0; j < 4; ++j) {
            int col = n0 + wn*64 + j*16 + lm;
            float4 v = {acc[i][j][0], acc[i][j][1], acc[i][j][2], acc[i][j][3]};
            *(float4*)(C + (size_t)col*2048 + row) = v;
        }
    }
}

// ---------------------------------------------------------------------------
// Fused MFMA gate kernel. Per block: 64 rows r=(m*32+b), full 384 gate cols.
// A row = [z(64) | h(128)] fp16, K=192 in 6 chunks of 32. B = Wcomb[384][192].
// Per wave: 16 rows x 384 cols; acc tiles: 16 combined (r,z gates, K=192)
// + 8 nx (K=0..63) + 8 nh (K=64..191) = 128 acc VGPRs.
// Epilogue: r=sig, zg=sig, n=tanh(nx + r*nh), h' = (1-zg)n + zg*h32.
// h32 is the fp32 master (update precision); h16 shadow feeds next GEMM.
__device__ __forceinline__ float sigmoidf_(float x) {
    return 1.f / (1.f + __expf(-x));
}
__global__ __launch_bounds__(256) void gatemm(
    const _Float16* __restrict__ Z16, int ldz, int zoff,
    const _Float16* __restrict__ H16r,
    const _Float16* __restrict__ Wcomb,
    const float* __restrict__ bc, const float* __restrict__ bhh,
    float* __restrict__ H32, _Float16* __restrict__ H16w)
{
    __shared__ __align__(16) _Float16 Asl[2048];    // [4 row-groups][512]
    __shared__ __align__(16) _Float16 Bsl[12288];   // [24 col-tiles][512]
    const int tid = threadIdx.x;
    const int wv = tid >> 6, lane = tid & 63;
    const int lm = lane & 15, lq = lane >> 4;
    const int r0 = blockIdx.x * 64;

    f32x4 acc_rz[16], acc_nx[8], acc_nh[8];
#pragma unroll
    for (int j = 0; j < 16; ++j) acc_rz[j] = (f32x4){0.f,0.f,0.f,0.f};
#pragma unroll
    for (int j = 0; j < 8; ++j) {
        acc_nx[j] = (f32x4){0.f,0.f,0.f,0.f};
        acc_nh[j] = (f32x4){0.f,0.f,0.f,0.f};
    }

    const int rA = r0 + wv*16 + lm;
    const int mA = rA >> 5, bA = rA & 31;
    const _Float16* zsrc = Z16 + (size_t)mA*ldz + zoff + bA*64 + lq*8;
    const _Float16* hsrc = H16r + (size_t)rA*128 + lq*8;

    for (int c = 0; c < 6; ++c) {
        const _Float16* asrc = (c < 2) ? (zsrc + c*32) : (hsrc + (c-2)*32);
        glds16(asrc, &Asl[wv*512]);
#pragma unroll
        for (int t = 0; t < 6; ++t) {
            int j = wv*6 + t;
            glds16(Wcomb + (size_t)(j*16 + lm)*192 + c*32 + lq*8, &Bsl[j*512]);
        }
        __syncthreads();
        half8 af = *(const half8*)&Asl[wv*512 + lane*8];
#pragma unroll
        for (int j = 0; j < 16; ++j) {
            half8 bf = *(const half8*)&Bsl[j*512 + lane*8];
            acc_rz[j] = __builtin_amdgcn_mfma_f32_16x16x32_f16(
                af, bf, acc_rz[j], 0, 0, 0);
        }
        if (c < 2) {
#pragma unroll
            for (int j = 0; j < 8; ++j) {
                half8 bf = *(const half8*)&Bsl[(16+j)*512 + lane*8];
                acc_nx[j] = __builtin_amdgcn_mfma_f32_16x16x32_f16(
                    af, bf, acc_nx[j], 0, 0, 0);
            }
        } else {
#pragma unroll
            for (int j = 0; j < 8; ++j) {
                half8 bf = *(const half8*)&Bsl[(16+j)*512 + lane*8];
                acc_nh[j] = __builtin_amdgcn_mfma_f32_16x16x32_f16(
                    af, bf, acc_nh[j], 0, 0, 0);
            }
        }
        __syncthreads();
    }
    // epilogue: lane owns cols o=j*16+lm, rows r0+wv*16+lq*4+reg
#pragma unroll
    for (int j = 0; j < 8; ++j) {
        int o = j*16 + lm;
        float br  = bc[o]       + bhh[o];
        float bz  = bc[o+128]   + bhh[o+128];
        float bnx = bc[o+256];
        float bnh = bhh[o+256];
#pragma unroll
        for (int reg = 0; reg < 4; ++reg) {
            int r = r0 + wv*16 + lq*4 + reg;
            size_t idx = (size_t)r*128 + o;
            float hold = H32[idx];
            float rg = sigmoidf_(acc_rz[j][reg] + br);
            float zg = sigmoidf_(acc_rz[j+8][reg] + bz);
            float ng = tanhf(acc_nx[j][reg] + bnx + rg*(acc_nh[j][reg] + bnh));
            float hn = (1.f - zg)*ng + zg*hold;
            H32[idx] = hn;
            H16w[idx] = (_Float16)hn;
        }
    }
}

// ---------------------------------------------------------------------------
// xfc[b][n] = h[r] . W_fc + b_fc ; also writes d_out[b][p][n]
__global__ __launch_bounds__(256) void fck(
    const float* __restrict__ h,
    const float* __restrict__ Wfc, const float* __restrict__ bfc,
    float* __restrict__ out_p,
    float* __restrict__ xfc)
{
    int w = (blockIdx.x * 256 + threadIdx.x) >> 6;
    int lane = threadIdx.x & 63;
    const float2* hr = (const float2*)(h + (size_t)w*HH);
    const float2* wf = (const float2*)Wfc;
    float2 a = hr[lane], b2 = wf[lane];
    float s = a.x*b2.x + a.y*b2.y;
#pragma unroll
    for (int off = 32; off; off >>= 1) s += __shfl_xor(s, off);
    if (lane == 0) {
        s += bfc[0];
        int n = w >> 5, b = w & 31;
        out_p[(size_t)b*(PP*NN) + n] = s;
        xfc[(size_t)b*NN + n] = s;
    }
}

// ---------------------------------------------------------------------------
extern "C" void kernel_launch(void* const* d_in, const int* in_sizes, int n_in,
                              void* d_out, int out_size, void* d_ws, size_t ws_size,
                              hipStream_t stream)
{
    const float* x    = (const float*)d_in[0];
    const float* adj  = (const float*)d_in[1];
    const float* Wg1  = (const float*)d_in[2];
    const float* bg1  = (const float*)d_in[3];
    const float* Wg2  = (const float*)d_in[4];
    const float* bg2  = (const float*)d_in[5];
    const float* Wih  = (const float*)d_in[6];
    const float* Whh  = (const float*)d_in[7];
    const float* bih  = (const float*)d_in[8];
    const float* bhh  = (const float*)d_in[9];
    const float* Wfc  = (const float*)d_in[10];
    const float* bfc  = (const float*)d_in[11];

    float* ws = (float*)d_ws;
    float* Wc   = ws;                              // 64*384
    float* bc   = Wc + GG*384;                     // 1024 (384 used)
    float* H32  = bc + 1024;                       // RR*HH fp32 (32 MB)
    float* xfc  = H32 + (size_t)RR*HH;             // NB*NN
    float* AXe  = xfc + (size_t)NB*NN;             // 4 partials x 384 x 2048
    float* AXd  = AXe + (size_t)4*384*NN;          // 4 partials x 128 x 2048
    _Float16* Ah    = (_Float16*)(AXd + (size_t)4*128*NN);  // 2048x2048
    _Float16* Xeh   = Ah    + (size_t)NN*NN;       // 384 x 2048
    _Float16* Xdh   = Xeh   + (size_t)384*NN;      // 128 x 2048
    _Float16* Hgh   = Xdh   + (size_t)128*NN;      // 6144 x 2048 (24 MB)
    _Float16* Z16   = Hgh   + (size_t)6144*NN;     // 2048 x 6144 (24 MB)
    _Float16* H16   = Z16   + (size_t)NN*6144;     // RR*HH fp16 (16 MB)
    _Float16* Wcomb = H16   + (size_t)RR*HH;       // 384*192
    // total ws use ~128 MiB

    hipMemsetAsync(H32, 0, (size_t)RR*HH*sizeof(float), stream);
    hipMemsetAsync(H16, 0, (size_t)RR*HH*sizeof(_Float16), stream);
    hipMemsetAsync(Xdh + (size_t)32*NN, 0, (size_t)96*NN*sizeof(_Float16), stream);

    cvtadj<<<2048, 256, 0, stream>>>(adj, Ah);
    wprep<<<98, 256, 0, stream>>>(Wg2, Wih, bih, bg2, Wc, bc);
    wprep2<<<288, 256, 0, stream>>>(Wc, Whh, Wcomb);
    xcvt_enc<<<384, 256, 0, stream>>>(x, Xeh);
    // encoder ax = adj @ Xe^T, all 12 steps (split-K 4, transposed fp32 C)
    gemm_mfma_T<<<dim3(3, 16, 4), 256, 0, stream>>>(
        Ah, Xeh, AXe, 512, (size_t)384*NN);

    float* outp = (float*)d_out;

    // encoder: 4 groups of 3 steps; z-GEMM batched per group (N=6144 cols)
    for (int g = 0; g < 4; ++g) {
        h1T<<<dim3(NN, 3), 256, 0, stream>>>(
            AXe, g*96, (size_t)384*NN, Wg1, bg1, Hgh);
        gemm_mfma<<<dim3(48, 16, 1), 256, 0, stream>>>(
            Ah, Hgh, Z16, 6144, 2048);
        for (int ty = 0; ty < 3; ++ty)
            gatemm<<<RR/64, 256, 0, stream>>>(
                Z16, 6144, ty*2048, H16, Wcomb, bc, bhh, H32, H16);
    }
    // decoder
    for (int p = 0; p < PP; ++p) {
        fck<<<RR/4, 256, 0, stream>>>(H32, Wfc, bfc, outp + (size_t)p*NN, xfc);
        if (p < PP-1) {
            xcvt_dec<<<32, 256, 0, stream>>>(xfc, Xdh);
            gemm_mfma_T<<<dim3(1, 16, 4), 256, 0, stream>>>(
                Ah, Xdh, AXd, 512, (size_t)128*NN);
            h1T<<<dim3(NN, 1), 256, 0, stream>>>(
                AXd, 0, (size_t)128*NN, Wg1, bg1, Hgh);
            gemm_mfma<<<dim3(16, 16, 1), 256, 0, stream>>>(
                Ah, Hgh, Z16, 2048, 2048);
            gatemm<<<RR/64, 256, 0, stream>>>(
                Z16, 2048, 0, H16, Wcomb, bc, bhh, H32, H16);
        }
    }
}

// Round 9
// 1272.675 us; speedup vs baseline: 7.9590x; 1.0896x over previous
//
#include <hip/hip_runtime.h>
#include <math.h>

// Problem constants: B=32, S=12, N=2048, F=1, H=128, G=64, O=1, P=3
#define NB 32
#define SS 12
#define NN 2048
#define HH 128
#define GG 64
#define PP 3
#define RR (NN*NB)   // 65536 rows, node-major r = n*32 + b

typedef __attribute__((ext_vector_type(8))) _Float16 half8;  // 8 fp16 (4 VGPRs)
typedef __attribute__((ext_vector_type(4))) float f32x4;

__device__ __forceinline__ void glds16(const void* g, const void* l) {
    __builtin_amdgcn_global_load_lds(
        (const __attribute__((address_space(1))) void*)g,
        (__attribute__((address_space(3))) void*)l, 16, 0, 0);
}

// ---------------------------------------------------------------------------
// fp32 -> fp16 (RNE), 8 elems/thread
__global__ __launch_bounds__(256) void cvtadj(
    const float* __restrict__ src, _Float16* __restrict__ dst)
{
    size_t i0 = ((size_t)blockIdx.x * 256 + threadIdx.x) * 8;
    float4 v0 = *(const float4*)(src + i0);
    float4 v1 = *(const float4*)(src + i0 + 4);
    union { _Float16 h[8]; uint4 q; } H;
    H.h[0]=(_Float16)v0.x; H.h[1]=(_Float16)v0.y;
    H.h[2]=(_Float16)v0.z; H.h[3]=(_Float16)v0.w;
    H.h[4]=(_Float16)v1.x; H.h[5]=(_Float16)v1.y;
    H.h[6]=(_Float16)v1.z; H.h[7]=(_Float16)v1.w;
    *(uint4*)(dst + i0) = H.q;
}

// Encoder x -> fp16 rows [(t*32+b)][n] from x[b][t][n]. 384 blocks.
__global__ __launch_bounds__(256) void xcvt_enc(
    const float* __restrict__ x, _Float16* __restrict__ dst)
{
    const int row = blockIdx.x;            // t*32 + b
    const int t = row >> 5, b = row & 31;
    const size_t n0 = (size_t)threadIdx.x * 8;
    const float* src = x + ((size_t)b*SS + t)*NN;
    float4 v0 = *(const float4*)(src + n0);
    float4 v1 = *(const float4*)(src + n0 + 4);
    union { _Float16 h[8]; uint4 q; } H;
    H.h[0]=(_Float16)v0.x; H.h[1]=(_Float16)v0.y;
    H.h[2]=(_Float16)v0.z; H.h[3]=(_Float16)v0.w;
    H.h[4]=(_Float16)v1.x; H.h[5]=(_Float16)v1.y;
    H.h[6]=(_Float16)v1.z; H.h[7]=(_Float16)v1.w;
    *(uint4*)(dst + (size_t)row*NN + n0) = H.q;
}

// ---------------------------------------------------------------------------
// Precompute Wc[64][384] = Wg2 @ Wih and bc[384] = bg2 @ Wih + bih.
__global__ __launch_bounds__(256) void wprep(
    const float* __restrict__ Wg2, const float* __restrict__ Wih,
    const float* __restrict__ bih, const float* __restrict__ bg2,
    float* __restrict__ Wc, float* __restrict__ bc)
{
    int idx = blockIdx.x * 256 + threadIdx.x;
    if (idx < GG*384) {
        int g = idx / 384, o = idx % 384;
        float s = 0.f;
        for (int k = 0; k < HH; ++k)
            s = fmaf(Wg2[g*HH + k], Wih[k*384 + o], s);
        Wc[idx] = s;
    } else if (idx < GG*384 + 384) {
        int o = idx - GG*384;
        float s = bih[o];
        for (int k = 0; k < HH; ++k)
            s = fmaf(bg2[k], Wih[k*384 + o], s);
        bc[o] = s;
    }
}

// Wcomb[o][k] fp16 (o=0..383, k=0..191): k<64 -> Wc[k][o], else Whh[k-64][o].
__global__ __launch_bounds__(256) void wprep2(
    const float* __restrict__ Wc, const float* __restrict__ Whh,
    _Float16* __restrict__ Wcomb)
{
    int idx = blockIdx.x * 256 + threadIdx.x;
    if (idx < 384*192) {
        int o = idx / 192, k = idx % 192;
        float v = (k < 64) ? Wc[k*384 + o] : Whh[(k-64)*384 + o];
        Wcomb[idx] = (_Float16)v;
    }
}

// ---------------------------------------------------------------------------
// h1 from ax partials: H[(ty*2048 + c)][n] = fp16(relu(ax[.]*W1[g]+b1[g])),
// c = b*64+g; ax row = col_base + ty*32 + b, summed over 4 split-K partials.
__global__ __launch_bounds__(256) void h1T(
    const float* __restrict__ axpart, int col_base, size_t part_stride,
    const float* __restrict__ Wg1, const float* __restrict__ bg1,
    _Float16* __restrict__ Hh)
{
    const int c = blockIdx.x;
    const int ty = blockIdx.y;
    const int b = c >> 6, g = c & 63;
    const float w1 = Wg1[g], b1 = bg1[g];
    const size_t n0 = (size_t)threadIdx.x * 8;
    const size_t rowoff = (size_t)(col_base + ty*32 + b) * NN + n0;
    float f[8] = {0,0,0,0,0,0,0,0};
#pragma unroll
    for (int p = 0; p < 4; ++p) {
        const float4* q = (const float4*)(axpart + p*part_stride + rowoff);
        float4 v0 = q[0], v1 = q[1];
        f[0]+=v0.x; f[1]+=v0.y; f[2]+=v0.z; f[3]+=v0.w;
        f[4]+=v1.x; f[5]+=v1.y; f[6]+=v1.z; f[7]+=v1.w;
    }
    union { _Float16 h[8]; uint4 q; } H;
#pragma unroll
    for (int k = 0; k < 8; ++k)
        H.h[k] = (_Float16)fmaxf(fmaf(f[k], w1, b1), 0.f);
    *(uint4*)(Hh + ((size_t)ty*2048 + c) * NN + n0) = H.q;
}

// ---------------------------------------------------------------------------
// Plain fp16 MFMA GEMM (m97 structure): C = A @ B^T, A[m][K], B[cols][K],
// fp16 k-contiguous. 128x128 tile, BK=64, global_load_lds 16B, 16x16x32 MFMA.
#define GEMM_BODY                                                              \
    __shared__ __align__(16) _Float16 As[8192];  /* 16 tiles x (16m x 32k) */  \
    __shared__ __align__(16) _Float16 Bs[8192];                                \
    const int tid  = threadIdx.x;                                              \
    const int wv   = tid >> 6, lane = tid & 63;                                \
    const int lm   = lane & 15, lq = lane >> 4;                                \
    const int m0   = blockIdx.y * 128;                                         \
    const int n0   = blockIdx.x * 128;                                         \
    const int wm   = wv >> 1, wn = wv & 1;                                     \
    f32x4 acc[4][4];                                                           \
    _Pragma("unroll")                                                          \
    for (int i = 0; i < 4; ++i)                                                \
        _Pragma("unroll")                                                      \
        for (int j = 0; j < 4; ++j) acc[i][j] = (f32x4){0.f,0.f,0.f,0.f};      \
    const int kbeg = blockIdx.z * kchunk, kend = kbeg + kchunk;                \
    for (int k0 = kbeg; k0 < kend; k0 += 64) {                                 \
        _Pragma("unroll")                                                      \
        for (int t = 0; t < 4; ++t) {                                          \
            int tt = wv*4 + t;                                                 \
            int rt = tt >> 1, kt = tt & 1;                                     \
            glds16(Ah + (size_t)(m0 + rt*16 + lm)*2048 + k0 + kt*32 + lq*8,    \
                   &As[tt*512]);                                               \
            glds16(Bh + (size_t)(n0 + rt*16 + lm)*2048 + k0 + kt*32 + lq*8,    \
                   &Bs[tt*512]);                                               \
        }                                                                      \
        __syncthreads();                                                       \
        _Pragma("unroll")                                                      \
        for (int ks = 0; ks < 2; ++ks) {                                       \
            half8 af[4], bf[4];                                                \
            _Pragma("unroll")                                                  \
            for (int i = 0; i < 4; ++i) {                                      \
                af[i] = *(const half8*)&As[((wm*4 + i)*2 + ks)*512 + lane*8];  \
                bf[i] = *(const half8*)&Bs[((wn*4 + i)*2 + ks)*512 + lane*8];  \
            }                                                                  \
            _Pragma("unroll")                                                  \
            for (int i = 0; i < 4; ++i)                                        \
                _Pragma("unroll")                                              \
                for (int j = 0; j < 4; ++j)                                    \
                    acc[i][j] = __builtin_amdgcn_mfma_f32_16x16x32_f16(        \
                        af[i], bf[j], acc[i][j], 0, 0, 0);                     \
        }                                                                      \
        __syncthreads();                                                       \
    }

// fp16-C epilogue: C[row*ldc + col] (z-GEMM; consumed by gatemm as fp16 A).
__global__ __launch_bounds__(256) void gemm_mfma(
    const _Float16* __restrict__ Ah, const _Float16* __restrict__ Bh,
    _Float16* __restrict__ C, int ldc, int kchunk)
{
    GEMM_BODY
    // C/D layout: col = lane&15, row = (lane>>4)*4 + reg
#pragma unroll
    for (int i = 0; i < 4; ++i) {
        int row = m0 + wm*64 + i*16 + lq*4;
#pragma unroll
        for (int j = 0; j < 4; ++j) {
            int col = n0 + wn*64 + j*16 + lm;
            _Float16* cp = C + (size_t)row*ldc + col;
            cp[0*(size_t)ldc] = (_Float16)acc[i][j][0];
            cp[1*(size_t)ldc] = (_Float16)acc[i][j][1];
            cp[2*(size_t)ldc] = (_Float16)acc[i][j][2];
            cp[3*(size_t)ldc] = (_Float16)acc[i][j][3];
        }
    }
}

// Transposed fp32 epilogue: C[col*2048 + row], float4 per (i,j). ax = adj@X^T.
__global__ __launch_bounds__(256) void gemm_mfma_T(
    const _Float16* __restrict__ Ah, const _Float16* __restrict__ Bh,
    float* __restrict__ Cbase, int kchunk, size_t partstride)
{
    float* C = Cbase + (size_t)blockIdx.z * partstride;
    GEMM_BODY
#pragma unroll
    for (int i = 0; i < 4; ++i) {
        int row = m0 + wm*64 + i*16 + lq*4;
#pragma unroll
        for (int j = 0; j < 4; ++j) {
            int col = n0 + wn*64 + j*16 + lm;
            float4 v = {acc[i][j][0], acc[i][j][1], acc[i][j][2], acc[i][j][3]};
            *(float4*)(C + (size_t)col*2048 + row) = v;
        }
    }
}

// ---------------------------------------------------------------------------
// Fused MFMA gate kernel. Per block: 64 rows r=(m*32+b), full 384 gate cols.
// A row = [z(64) | h(128)] fp16, K=192 in 6 chunks of 32. B = Wcomb[384][192].
// h lives fp16-only (H16 master): the GRU recurrence err ~ z*err + delta
// bounds fp16 rounding at ~1e-3 relative, ~4e-8 absolute at the output.
__device__ __forceinline__ float sigmoidf_(float x) {
    return 1.f / (1.f + __expf(-x));
}
__global__ __launch_bounds__(256) void gatemm(
    const _Float16* __restrict__ Z16, int ldz, int zoff,
    const _Float16* __restrict__ Wcomb,
    const float* __restrict__ bc, const float* __restrict__ bhh,
    _Float16* __restrict__ H16)          // read + in-place update (own rows)
{
    __shared__ __align__(16) _Float16 Asl[2048];    // [4 row-groups][512]
    __shared__ __align__(16) _Float16 Bsl[12288];   // [24 col-tiles][512]
    const int tid = threadIdx.x;
    const int wv = tid >> 6, lane = tid & 63;
    const int lm = lane & 15, lq = lane >> 4;
    const int r0 = blockIdx.x * 64;

    f32x4 acc_rz[16], acc_nx[8], acc_nh[8];
#pragma unroll
    for (int j = 0; j < 16; ++j) acc_rz[j] = (f32x4){0.f,0.f,0.f,0.f};
#pragma unroll
    for (int j = 0; j < 8; ++j) {
        acc_nx[j] = (f32x4){0.f,0.f,0.f,0.f};
        acc_nh[j] = (f32x4){0.f,0.f,0.f,0.f};
    }

    const int rA = r0 + wv*16 + lm;
    const int mA = rA >> 5, bA = rA & 31;
    const _Float16* zsrc = Z16 + (size_t)mA*ldz + zoff + bA*64 + lq*8;
    const _Float16* hsrc = H16 + (size_t)rA*128 + lq*8;

    for (int c = 0; c < 6; ++c) {
        const _Float16* asrc = (c < 2) ? (zsrc + c*32) : (hsrc + (c-2)*32);
        glds16(asrc, &Asl[wv*512]);
#pragma unroll
        for (int t = 0; t < 6; ++t) {
            int j = wv*6 + t;
            glds16(Wcomb + (size_t)(j*16 + lm)*192 + c*32 + lq*8, &Bsl[j*512]);
        }
        __syncthreads();
        half8 af = *(const half8*)&Asl[wv*512 + lane*8];
#pragma unroll
        for (int j = 0; j < 16; ++j) {
            half8 bf = *(const half8*)&Bsl[j*512 + lane*8];
            acc_rz[j] = __builtin_amdgcn_mfma_f32_16x16x32_f16(
                af, bf, acc_rz[j], 0, 0, 0);
        }
        if (c < 2) {
#pragma unroll
            for (int j = 0; j < 8; ++j) {
                half8 bf = *(const half8*)&Bsl[(16+j)*512 + lane*8];
                acc_nx[j] = __builtin_amdgcn_mfma_f32_16x16x32_f16(
                    af, bf, acc_nx[j], 0, 0, 0);
            }
        } else {
#pragma unroll
            for (int j = 0; j < 8; ++j) {
                half8 bf = *(const half8*)&Bsl[(16+j)*512 + lane*8];
                acc_nh[j] = __builtin_amdgcn_mfma_f32_16x16x32_f16(
                    af, bf, acc_nh[j], 0, 0, 0);
            }
        }
        __syncthreads();
    }
    // epilogue: lane owns cols o=j*16+lm, rows r0+wv*16+lq*4+reg
#pragma unroll
    for (int j = 0; j < 8; ++j) {
        int o = j*16 + lm;
        float br  = bc[o]       + bhh[o];
        float bz  = bc[o+128]   + bhh[o+128];
        float bnx = bc[o+256];
        float bnh = bhh[o+256];
#pragma unroll
        for (int reg = 0; reg < 4; ++reg) {
            int r = r0 + wv*16 + lq*4 + reg;
            size_t idx = (size_t)r*128 + o;
            float hold = (float)H16[idx];
            float rg = sigmoidf_(acc_rz[j][reg] + br);
            float zg = sigmoidf_(acc_rz[j+8][reg] + bz);
            float ng = tanhf(acc_nx[j][reg] + bnx + rg*(acc_nh[j][reg] + bnh));
            H16[idx] = (_Float16)((1.f - zg)*ng + zg*hold);
        }
    }
}

// ---------------------------------------------------------------------------
// fck: s = h16[r] . W_fc + b_fc ; writes d_out[b][p][n] fp32 AND the decoder's
// next-step X row Xdh[b][n] fp16 (replaces the old xfc+xcvt_dec pair).
__global__ __launch_bounds__(256) void fck(
    const _Float16* __restrict__ h,
    const float* __restrict__ Wfc, const float* __restrict__ bfc,
    float* __restrict__ out_p,
    _Float16* __restrict__ Xdh)
{
    int w = (blockIdx.x * 256 + threadIdx.x) >> 6;
    int lane = threadIdx.x & 63;
    const _Float16* hr = h + (size_t)w*HH + lane*2;
    const float2* wf = (const float2*)Wfc;
    float2 b2 = wf[lane];
    float s = (float)hr[0]*b2.x + (float)hr[1]*b2.y;
#pragma unroll
    for (int off = 32; off; off >>= 1) s += __shfl_xor(s, off);
    if (lane == 0) {
        s += bfc[0];
        int n = w >> 5, b = w & 31;
        out_p[(size_t)b*(PP*NN) + n] = s;
        Xdh[(size_t)b*NN + n] = (_Float16)s;
    }
}

// ---------------------------------------------------------------------------
extern "C" void kernel_launch(void* const* d_in, const int* in_sizes, int n_in,
                              void* d_out, int out_size, void* d_ws, size_t ws_size,
                              hipStream_t stream)
{
    const float* x    = (const float*)d_in[0];
    const float* adj  = (const float*)d_in[1];
    const float* Wg1  = (const float*)d_in[2];
    const float* bg1  = (const float*)d_in[3];
    const float* Wg2  = (const float*)d_in[4];
    const float* bg2  = (const float*)d_in[5];
    const float* Wih  = (const float*)d_in[6];
    const float* Whh  = (const float*)d_in[7];
    const float* bih  = (const float*)d_in[8];
    const float* bhh  = (const float*)d_in[9];
    const float* Wfc  = (const float*)d_in[10];
    const float* bfc  = (const float*)d_in[11];

    float* ws = (float*)d_ws;
    float* Wc   = ws;                              // 64*384
    float* bc   = Wc + GG*384;                     // 1024 (384 used)
    float* AXe  = bc + 1024;                       // 4 partials x 384 x 2048
    float* AXd  = AXe + (size_t)4*384*NN;          // 4 partials x 128 x 2048
    _Float16* Ah    = (_Float16*)(AXd + (size_t)4*128*NN);  // 2048x2048 (8 MB)
    _Float16* Xeh   = Ah    + (size_t)NN*NN;       // 384 x 2048
    _Float16* Xdh   = Xeh   + (size_t)384*NN;      // 128 x 2048
    _Float16* Hgh   = Xdh   + (size_t)128*NN;      // 6144 x 2048 (24 MB)
    _Float16* Z16   = Hgh   + (size_t)6144*NN;     // 2048 x 6144 (24 MB)
    _Float16* H16   = Z16   + (size_t)NN*6144;     // RR*HH fp16 (16 MB) master
    _Float16* Wcomb = H16   + (size_t)RR*HH;       // 384*192
    // total ws use ~92 MiB

    hipMemsetAsync(H16, 0, (size_t)RR*HH*sizeof(_Float16), stream);
    hipMemsetAsync(Xdh + (size_t)32*NN, 0, (size_t)96*NN*sizeof(_Float16), stream);

    cvtadj<<<2048, 256, 0, stream>>>(adj, Ah);
    wprep<<<98, 256, 0, stream>>>(Wg2, Wih, bih, bg2, Wc, bc);
    wprep2<<<288, 256, 0, stream>>>(Wc, Whh, Wcomb);
    xcvt_enc<<<384, 256, 0, stream>>>(x, Xeh);
    // encoder ax = adj @ Xe^T, all 12 steps (split-K 4, transposed fp32 C)
    gemm_mfma_T<<<dim3(3, 16, 4), 256, 0, stream>>>(
        Ah, Xeh, AXe, 512, (size_t)384*NN);

    float* outp = (float*)d_out;

    // encoder: 4 groups of 3 steps; z-GEMM batched per group (N=6144 cols)
    for (int g = 0; g < 4; ++g) {
        h1T<<<dim3(NN, 3), 256, 0, stream>>>(
            AXe, g*96, (size_t)384*NN, Wg1, bg1, Hgh);
        gemm_mfma<<<dim3(48, 16, 1), 256, 0, stream>>>(
            Ah, Hgh, Z16, 6144, 2048);
        for (int ty = 0; ty < 3; ++ty)
            gatemm<<<RR/64, 256, 0, stream>>>(
                Z16, 6144, ty*2048, Wcomb, bc, bhh, H16);
    }
    // decoder
    for (int p = 0; p < PP; ++p) {
        fck<<<RR/4, 256, 0, stream>>>(H16, Wfc, bfc, outp + (size_t)p*NN, Xdh);
        if (p < PP-1) {
            gemm_mfma_T<<<dim3(1, 16, 4), 256, 0, stream>>>(
                Ah, Xdh, AXd, 512, (size_t)128*NN);
            h1T<<<dim3(NN, 1), 256, 0, stream>>>(
                AXd, 0, (size_t)128*NN, Wg1, bg1, Hgh);
            gemm_mfma<<<dim3(16, 16, 1), 256, 0, stream>>>(
                Ah, Hgh, Z16, 2048, 2048);
            gatemm<<<RR/64, 256, 0, stream>>>(
                Z16, 2048, 0, Wcomb, bc, bhh, H16);
        }
    }
}